// Round 1
// baseline (773.149 us; speedup 1.0000x reference)
//
#include <hip/hip_runtime.h>
#include <stdint.h>
#include <string.h>
#include <cmath>

// SpikingYOLO round 18: conv3 -> MFMA (bf16 3-term Dekker weight split).
// Layer-1/2 numerics BIT-IDENTICAL to R17 (conv1, conv2 chains, lif_s2 ops
// unchanged; only memory layouts moved). Layer-3 conv now = f32-accumulated
// MFMA over {hi,mid,lo} bf16 weight terms (~24-bit effective weight
// precision); spikes (0/1) are exact in bf16. Spike plane for L3 stored as
// [f][row][col][ci] u8 (ci innermost) so MFMA A-fragments are single
// global_load_dwordx2; weights pre-split into [term][tap][co][ci] bf16 with
// the in-register u8->bf16 element perm {0,2,1,3,4,6,5,7} folded in.

#define BB 4
#define TT 10

typedef short bf16x8 __attribute__((ext_vector_type(8)));
typedef float f32x4  __attribute__((ext_vector_type(4)));

// padded u8 plane geometry for L2 input (s1p): HIN=128: row stride 136 B,
// plane 129*136 = 17544 B (rows -1..127, cols -4..131)

// ------------------------------------------------ zero the pad borders (s1p)
template<int RS_DW, int NROWS>
__global__ __launch_bounds__(256) void zpad(uint32_t* __restrict__ buf) {
    const int plane = blockIdx.x;
    const int j = threadIdx.x;
    uint32_t* p = buf + (size_t)plane * (RS_DW * NROWS);
    if (j < NROWS) p[j * RS_DW] = 0u;                    // cols -4..-1 of every row
    const int k = j - NROWS;
    if (k >= 0 && k < RS_DW - 1) p[k + 1] = 0u;          // rest of top pad row (-1)
}

// ---------------- zero pads of s2pt: [40][65 rows][65 cols][128 ci] u8.
// row 0 = input row -1, col 0 = input col -1. Per frame: row0 (8320 B) +
// col0 of every row (128 B each). Plane = 65*8320 = 540800 B = 135200 u32.
__global__ __launch_bounds__(256) void zpad3(uint32_t* __restrict__ buf) {
    uint32_t* p = buf + (size_t)blockIdx.x * 135200u;
    for (int i = threadIdx.x; i < 4160; i += 256) {
        if (i < 2080) p[i] = 0u;                          // row 0
        else { int j = i - 2080; p[(j >> 5) * 2080 + (j & 31)] = 0u; }  // col 0
    }
}

// ---------------------------------------------------------------- conv1+LIF
// unchanged numerics from R9; writes u8 spikes into padded s1p layout.
__global__ __launch_bounds__(256) void conv1_lif(
    const float* __restrict__ x,    // [4,2,128,128,10]
    const float* __restrict__ w1,   // [64,2,3,3]
    const float* __restrict__ b1,   // [64]
    uint8_t* __restrict__ s1p,      // padded [40*64][129][136]
    float alpha, float beta)
{
    __shared__ float xs[2][3][10][10];   // [ci][kh][wi][t]
    __shared__ float wsh[18][64];        // [tap][co]
    const int tid = threadIdx.x;
    const int b = blockIdx.z, h = blockIdx.y, w0 = blockIdx.x * 8;

    for (int i = tid; i < 1152; i += 256) {
        int co = i & 63, tap = i >> 6;
        wsh[tap][co] = w1[co * 18 + tap];
    }
    for (int i = tid; i < 600; i += 256) {
        int t = i % 10; int rest = i / 10;
        int wi = rest % 10; rest /= 10;
        int kh = rest % 3; int ci = rest / 3;
        int hh = h - 1 + kh, ww = w0 - 1 + wi;
        float v = 0.f;
        if (hh >= 0 && hh < 128 && ww >= 0 && ww < 128)
            v = x[(((b * 2 + ci) * 128 + hh) * 128 + ww) * 10 + t];
        xs[ci][kh][wi][t] = v;
    }
    __syncthreads();

    const int px  = tid & 7;
    const int cog = (tid >> 3) * 2;
    float acc[2][10];
#pragma unroll
    for (int c = 0; c < 2; ++c)
#pragma unroll
        for (int t = 0; t < 10; ++t) acc[c][t] = 0.f;

#pragma unroll
    for (int tap = 0; tap < 18; ++tap) {
        const int ci = tap / 9, kh = (tap % 9) / 3, kw = tap % 3;
        float2 wv = *(const float2*)&wsh[tap][cog];
#pragma unroll
        for (int t = 0; t < 10; ++t) {
            float xv = xs[ci][kh][px + kw][t];
            acc[0][t] = __fmaf_rn(wv.x, xv, acc[0][t]);
            acc[1][t] = __fmaf_rn(wv.y, xv, acc[1][t]);
        }
    }
#pragma unroll
    for (int c = 0; c < 2; ++c) {
        const float bv = b1[cog + c];
        float syn = 0.f, mem = 0.f;
#pragma unroll
        for (int t = 0; t < 10; ++t) {
            float cur = __fadd_rn(acc[c][t], bv);
            syn = __fadd_rn(__fmul_rn(beta, syn), cur);
            mem = __fadd_rn(__fmul_rn(alpha, mem), syn);
            float sp = (mem >= 1.0f) ? 1.0f : 0.0f;
            mem = __fsub_rn(mem, sp);
            s1p[(uint32_t)((t * BB + b) * 64 + (cog + c)) * 17544u
                + (h + 1) * 136 + (w0 + px + 4)] = (uint8_t)sp;
        }
    }
}

// --------------------------------------------------- weight transpose (wt2)
__global__ __launch_bounds__(256) void wtrans(
    const float* __restrict__ w, float* __restrict__ wt, int K, int COUT)
{
    int i = blockIdx.x * 256 + threadIdx.x;
    if (i < K * COUT) {
        int k = i / COUT, co = i - k * COUT;
        wt[i] = w[co * K + k];
    }
}

// --------- w3 -> 3-term bf16 split, layout [term][tap][co][ci], with the
// u8->bf16 convert perm folded in (swap ci-in-granule positions 1<->2, 5<->6).
__global__ __launch_bounds__(256) void wtrans3b(
    const float* __restrict__ w3, unsigned short* __restrict__ wtb)
{
    int i = blockIdx.x * 256 + threadIdx.x;
    if (i >= 294912) return;                 // 256*128*9
    int co  = i / 1152;
    int rem = i - co * 1152;
    int ci  = rem / 9;
    int tap = rem - ci * 9;                  // kh*3+kw
    float w = w3[i];                         // [co][ci][kh][kw]
    uint32_t uw  = __float_as_uint(w);
    uint32_t h16 = (uw + 0x7FFFu + ((uw >> 16) & 1u)) >> 16;   // RNE bf16
    float hf = __uint_as_float(h16 << 16);
    float r1 = w - hf;                                          // exact
    uint32_t ur1 = __float_as_uint(r1);
    uint32_t m16 = (ur1 + 0x7FFFu + ((ur1 >> 16) & 1u)) >> 16;
    float mf = __uint_as_float(m16 << 16);
    float r2 = r1 - mf;                                         // exact
    uint32_t ur2 = __float_as_uint(r2);
    uint32_t l16 = (ur2 + 0x7FFFu + ((ur2 >> 16) & 1u)) >> 16;
    int cim = ci & 3;
    int ci2 = (cim == 1 || cim == 2) ? (ci ^ 3) : ci;           // perm fold
    size_t base = (size_t)(tap * 256 + co) * 128 + ci2;
    wtb[base]            = (unsigned short)h16;
    wtb[base + 294912]   = (unsigned short)m16;
    wtb[base + 2*294912] = (unsigned short)l16;
}

// -------------------------------- per-ci conv taps, 16co x 4px (u8 input)
template<int COUT, int PLANE, int KHB, int KHE>
__device__ __forceinline__ void conv_ci16(
    int ci, const uint8_t* __restrict__ fb, const float* __restrict__ wt,
    int cob, const int off[3], float part[64])
{
    const uint8_t* p = fb + (uint32_t)ci * PLANE;
    uint32_t d0[3], d1[3], d2[3];
#pragma unroll
    for (int kh = KHB; kh < KHE; ++kh) {
        const uint8_t* q = p + off[kh];
        uint2 v = *(const uint2*)q;
        d0[kh] = v.x; d1[kh] = v.y;
        d2[kh] = *(const uint32_t*)(q + 8);
    }
#pragma unroll
    for (int kh = KHB; kh < KHE; ++kh) {
        float sv[9];
        sv[0] = (float)(d0[kh] >> 24);
        sv[1] = (float)(d1[kh] & 0xffu);
        sv[2] = (float)((d1[kh] >> 8) & 0xffu);
        sv[3] = (float)((d1[kh] >> 16) & 0xffu);
        sv[4] = (float)(d1[kh] >> 24);
        sv[5] = (float)(d2[kh] & 0xffu);
        sv[6] = (float)((d2[kh] >> 8) & 0xffu);
        sv[7] = (float)((d2[kh] >> 16) & 0xffu);
        sv[8] = (float)(d2[kh] >> 24);
#pragma unroll
        for (int kw = 0; kw < 3; ++kw) {
            const float* wp = wt + (ci * 9 + kh * 3 + kw) * COUT + cob;
#pragma unroll
            for (int co = 0; co < 16; ++co) {
                const float wv = wp[co];
#pragma unroll
                for (int j = 0; j < 4; ++j)
                    part[co * 4 + j] = __fmaf_rn(wv, sv[2 * j + kw], part[co * 4 + j]);
            }
        }
    }
}

// ------------------- L2 conv, chain-split (numerics identical to R17).
// NEW epilogue layout: partials stored [f][px(4096)][co(128)] so lif_s2_t can
// consume 4 consecutive co per thread and emit ci-innermost spike bytes.
__global__ __launch_bounds__(256) void conv2_chains(
    const uint8_t* __restrict__ sin,   // s1p padded [40*64][129][136]
    const float* __restrict__ wt,      // [576][128]
    float* __restrict__ p0, float* __restrict__ p1)
{
    const int tid = threadIdx.x;
    const int zc  = blockIdx.z / 40;
    const int f   = blockIdx.z - zc * 40;
    const int w4  = tid & 15;            // 16 w-groups x 4px = 64 cols
    const int hh  = blockIdx.x * 16 + (tid >> 4);
    const int cob = blockIdx.y * 16;

    const uint8_t* fb = sin + (size_t)f * 64 * 17544;
    int off[3];
#pragma unroll
    for (int kh = 0; kh < 3; ++kh) off[kh] = (2 * hh + kh) * 136 + 8 * w4;

    float part[64];
#pragma unroll
    for (int n = 0; n < 64; ++n) part[n] = 0.f;

    float* outp;
    if (zc == 0) {
        for (int ci = 0; ci < 42; ++ci)
            conv_ci16<128,17544,0,3>(ci, fb, wt, cob, off, part);
        conv_ci16<128,17544,0,2>(42, fb, wt, cob, off, part);
        outp = p0;
    } else {
        conv_ci16<128,17544,2,3>(42, fb, wt, cob, off, part);
        for (int ci = 43; ci < 64; ++ci)
            conv_ci16<128,17544,0,3>(ci, fb, wt, cob, off, part);
        outp = p1;
    }

#pragma unroll
    for (int j = 0; j < 4; ++j) {
        float* op = &outp[((uint32_t)f * 4096u + (uint32_t)(hh * 64 + 4 * w4 + j)) * 128u + cob];
#pragma unroll
        for (int a = 0; a < 4; ++a)
            *(float4*)(op + 4 * a) = make_float4(part[(4*a+0)*4+j], part[(4*a+1)*4+j],
                                                 part[(4*a+2)*4+j], part[(4*a+3)*4+j]);
    }
}

// ---------------------- LIF from 2 chain partials -> u8 spikes, layer 2.
// Same ops per (co,px,t) as R17 lif_s2 (bit-exact spikes); thread now owns
// 4 consecutive co at one px; writes s2pt[f][h+1][w+1][co0..co0+3] as u32.
__global__ __launch_bounds__(256) void lif_s2_t(
    const float* __restrict__ pa, const float* __restrict__ pb,
    const float* __restrict__ bias,
    uint8_t* __restrict__ s2pt, float alpha, float beta)
{
    const int tid = threadIdx.x;
    const int b   = blockIdx.z;
    const int px  = blockIdx.x * 8 + (tid >> 5);
    const int co0 = (tid & 31) * 4;
    const int h = px >> 6, w = px & 63;
    float4 bv = *(const float4*)&bias[co0];
    const float bva[4] = {bv.x, bv.y, bv.z, bv.w};
    float syn[4] = {0.f,0.f,0.f,0.f}, mem[4] = {0.f,0.f,0.f,0.f};
    uint8_t* sp = s2pt + (uint32_t)(h + 1) * 8320u + (uint32_t)(w + 1) * 128u + co0;
    for (int t = 0; t < TT; ++t) {
        const int f = t * BB + b;
        const uint32_t idx = ((uint32_t)f * 4096u + px) * 128u + co0;
        float4 A = *(const float4*)&pa[idx];
        float4 B = *(const float4*)&pb[idx];
        const float va[4] = {A.x, A.y, A.z, A.w};
        const float vb[4] = {B.x, B.y, B.z, B.w};
        uint32_t pk = 0;
#pragma unroll
        for (int j = 0; j < 4; ++j) {
            float conv = __fadd_rn(__fadd_rn(0.0f, va[j]), vb[j]);
            float c = __fadd_rn(conv, bva[j]);
            syn[j] = __fadd_rn(__fmul_rn(beta, syn[j]), c);
            mem[j] = __fadd_rn(__fmul_rn(alpha, mem[j]), syn[j]);
            bool sc = (mem[j] >= 1.0f);
            mem[j] = __fsub_rn(mem[j], sc ? 1.0f : 0.0f);
            pk |= (sc ? 1u : 0u) << (j * 8);
        }
        *(uint32_t*)(sp + (uint32_t)f * 540800u) = pk;
    }
}

// --------- u8 spikes (8 bytes = 8 ci) -> bf16x8 A-fragment, element order
// {0,2,1,3,4,6,5,7} (folded into weight layout). b*0x3F80 = bf16(b), b in {0,1}.
__device__ __forceinline__ bf16x8 spikes_to_bf16(uint2 s) {
    union { uint32_t u[4]; bf16x8 v; } t;
    t.u[0] = (s.x & 0x00FF00FFu) * 0x3F80u;          // ci 0,2
    t.u[1] = ((s.x >> 8) & 0x00FF00FFu) * 0x3F80u;   // ci 1,3
    t.u[2] = (s.y & 0x00FF00FFu) * 0x3F80u;          // ci 4,6
    t.u[3] = ((s.y >> 8) & 0x00FF00FFu) * 0x3F80u;   // ci 5,7
    return t.v;
}

// ------------------- L3 conv via MFMA 16x16x32 bf16, 3-term weight split.
// Block: 4 waves x 1 output row h; wave computes 32 px (2 M-tiles) x 64 co
// (4 N-tiles). A = spikes [px][k=ci], B = weights [k][co], D[px][co].
// K-loop: 9 taps x 4 ci-chunks of 32; per chunk 2 A-loads (dwordx2, no LDS)
// reused over 4 N x 3 terms = 24 MFMAs. Output: single f32 buffer [f][co][px].
__global__ __launch_bounds__(256) void conv3_mfma(
    const uint8_t* __restrict__ s2pt,       // [40][65][65][128] u8
    const unsigned short* __restrict__ wtb, // [3][9][256][128] bf16
    float* __restrict__ p3)                 // [40][256][32][32]
{
    const int tid  = threadIdx.x;
    const int lane = tid & 63;
    const int wid  = tid >> 6;
    const int r = lane & 15, g = lane >> 4;
    const int f   = blockIdx.z;
    const int cob = blockIdx.y * 64;
    const int h   = blockIdx.x * 4 + wid;

    const uint8_t* fbase = s2pt + (uint32_t)f * 540800u;

    f32x4 acc[2][4];
#pragma unroll
    for (int mt = 0; mt < 2; ++mt)
#pragma unroll
        for (int n = 0; n < 4; ++n) acc[mt][n] = (f32x4){0.f, 0.f, 0.f, 0.f};

    for (int tap = 0; tap < 9; ++tap) {
        const int kh = tap / 3, kw = tap - kh * 3;
        // input row index = 2h+kh-1 -> stored row 2h+kh; col = 2w+kw -> byte w*256+kw*128
        const uint8_t* rp = fbase + (uint32_t)(2 * h + kh) * 8320u
                          + (uint32_t)kw * 128u + (uint32_t)r * 256u + (uint32_t)g * 8u;
        const unsigned short* wrow = wtb + (uint32_t)(tap * 256 + cob + r) * 128u + g * 8;
#pragma unroll
        for (int c = 0; c < 4; ++c) {
            bf16x8 a0 = spikes_to_bf16(*(const uint2*)(rp + c * 32));
            bf16x8 a1 = spikes_to_bf16(*(const uint2*)(rp + 4096 + c * 32));
#pragma unroll
            for (int n = 0; n < 4; ++n) {
                const unsigned short* wp = wrow + n * 2048 + c * 32;
#pragma unroll
                for (int term = 0; term < 3; ++term) {
                    bf16x8 bfr = *(const bf16x8*)(wp + term * 294912);
                    acc[0][n] = __builtin_amdgcn_mfma_f32_16x16x32_bf16(a0, bfr, acc[0][n], 0, 0, 0);
                    acc[1][n] = __builtin_amdgcn_mfma_f32_16x16x32_bf16(a1, bfr, acc[1][n], 0, 0, 0);
                }
            }
        }
    }

    // D: row=(lane>>4)*4+reg -> w = mt*16 + g*4 + reg; col=lane&15 -> co
#pragma unroll
    for (int mt = 0; mt < 2; ++mt)
#pragma unroll
        for (int n = 0; n < 4; ++n) {
            float* op = p3 + ((uint32_t)(f * 256 + cob + n * 16 + r) * 32u + h) * 32u
                      + mt * 16 + g * 4;
            *(f32x4*)op = acc[mt][n];
        }
}

// ---------------------- LIF + time-mean from the single conv3 buffer
__global__ __launch_bounds__(256) void lif_mean1(
    const float* __restrict__ p3, const float* __restrict__ bias,
    float* __restrict__ pooled, float alpha, float beta)
{
    const int px = (blockIdx.x * 256 + threadIdx.x) * 4;
    const int co = blockIdx.y;
    const int b  = blockIdx.z;
    const float bv = bias[co];
    float syn[4] = {0.f,0.f,0.f,0.f}, mem[4] = {0.f,0.f,0.f,0.f};
    float sum[4] = {0.f,0.f,0.f,0.f};
    for (int t = 0; t < TT; ++t) {
        const int idx = ((t * BB + b) * 256 + co) * 1024 + px;
        float4 a = *(const float4*)&p3[idx];
        const float va[4] = {a.x, a.y, a.z, a.w};
#pragma unroll
        for (int j = 0; j < 4; ++j) {
            float cu = __fadd_rn(va[j], bv);
            syn[j] = __fadd_rn(__fmul_rn(beta, syn[j]), cu);
            mem[j] = __fadd_rn(__fmul_rn(alpha, mem[j]), syn[j]);
            bool sc = (mem[j] >= 1.0f);
            float sp = sc ? 1.0f : 0.0f;
            mem[j] = __fsub_rn(mem[j], sp);
            sum[j] = __fadd_rn(sum[j], sp);
        }
    }
    *(float4*)&pooled[(b * 256 + co) * 1024 + px] =
        make_float4(sum[0] / 10.0f, sum[1] / 10.0f, sum[2] / 10.0f, sum[3] / 10.0f);
}

// ------------------------------------------------------------------ det 1x1
__global__ __launch_bounds__(256) void det_conv(
    const float* __restrict__ pooled, // [4,256,1024]
    const float* __restrict__ wd,     // [255,256]
    const float* __restrict__ bd,     // [255]
    float* __restrict__ out)          // [4,255,1024]
{
    __shared__ float wtl[16][64];
    __shared__ float ps[16][64];
    const int tid = threadIdx.x;
    const int b = blockIdx.z;
    const int o_base = blockIdx.y * 64;
    const int px_base = blockIdx.x * 64;
    const int o_off = (tid >> 4) * 4;
    const int px_off = (tid & 15) * 4;
    float acc[4][4];
#pragma unroll
    for (int c = 0; c < 4; ++c) {
        int o = o_base + o_off + c;
        float bv = (o < 255) ? bd[o] : 0.f;
#pragma unroll
        for (int j = 0; j < 4; ++j) acc[c][j] = bv;
    }
    for (int cc = 0; cc < 16; ++cc) {
        for (int k = tid; k < 1024; k += 256) {
            int o = k & 63, ci = k >> 6;
            wtl[ci][o] = (o_base + o < 255) ? wd[(o_base + o) * 256 + cc * 16 + ci] : 0.f;
            ps[ci][o] = pooled[(b * 256 + cc * 16 + ci) * 1024 + px_base + o];
        }
        __syncthreads();
#pragma unroll
        for (int ci = 0; ci < 16; ++ci) {
            float4 wv = *(const float4*)&wtl[ci][o_off];
            float4 sv = *(const float4*)&ps[ci][px_off];
            acc[0][0] += wv.x * sv.x; acc[0][1] += wv.x * sv.y;
            acc[0][2] += wv.x * sv.z; acc[0][3] += wv.x * sv.w;
            acc[1][0] += wv.y * sv.x; acc[1][1] += wv.y * sv.y;
            acc[1][2] += wv.y * sv.z; acc[1][3] += wv.y * sv.w;
            acc[2][0] += wv.z * sv.x; acc[2][1] += wv.z * sv.y;
            acc[2][2] += wv.z * sv.z; acc[2][3] += wv.z * sv.w;
            acc[3][0] += wv.w * sv.x; acc[3][1] += wv.w * sv.y;
            acc[3][2] += wv.w * sv.z; acc[3][3] += wv.w * sv.w;
        }
        __syncthreads();
    }
#pragma unroll
    for (int c = 0; c < 4; ++c) {
        int o = o_base + o_off + c;
        if (o < 255)
            *(float4*)&out[(b * 255 + o) * 1024 + px_base + px_off] =
                make_float4(acc[c][0], acc[c][1], acc[c][2], acc[c][3]);
    }
}

extern "C" void kernel_launch(void* const* d_in, const int* in_sizes, int n_in,
                              void* d_out, int out_size, void* d_ws, size_t ws_size,
                              hipStream_t stream) {
    const float* x  = (const float*)d_in[0];
    const float* w1 = (const float*)d_in[1];
    const float* b1 = (const float*)d_in[2];
    const float* w2 = (const float*)d_in[3];
    const float* b2 = (const float*)d_in[4];
    const float* w3 = (const float*)d_in[5];
    const float* b3 = (const float*)d_in[6];
    const float* wd = (const float*)d_in[7];
    const float* bd = (const float*)d_in[8];
    float* out = (float*)d_out;

    // ws layout with aliasing (lifetimes; ~236.4 MB):
    //   s1p  u8 [2560][17544]   @ 256          (44,912,640)  conv1 -> conv2
    //   p3   f32 [40*256*1024]  @ 256          (41,943,040)  conv3 -> lif_mean1 (overlays s1p)
    //   p2a  f32 [40][4096][128]@ 44,912,896   (83,886,080)  conv2 -> lif_s2_t
    //   pooled f32              @ 44,912,896   (4,194,304)   lif_mean1 -> det (overlays p2a)
    //   p2b  f32                @ 128,798,976  (83,886,080)  conv2 -> lif_s2_t
    //   s2pt u8 [40][65][65][128]@212,685,056  (21,632,000)  lif_s2_t -> conv3
    //   wt2  f32 [576][128]     @ 234,317,056  (294,912)
    //   wt3b bf16 [3][9][256][128]@234,611,968 (1,769,472)   end 236,381,440
    uint8_t* wsb = (uint8_t*)d_ws;
    uint8_t* s1p    = wsb + 256;
    float*   p3     = (float*)(wsb + 256);
    float*   p2a    = (float*)(wsb + 44912896u);
    float*   pooled = (float*)(wsb + 44912896u);
    float*   p2b    = (float*)(wsb + 128798976u);
    uint8_t* s2pt   = wsb + 212685056u;
    float*   wt2    = (float*)(wsb + 234317056u);
    unsigned short* wt3b = (unsigned short*)(wsb + 234611968u);

    float alpha, beta;
    { uint32_t ab = 0x3F7383C6u; memcpy(&alpha, &ab, 4); }  // e^-0.05f
    { uint32_t bb = 0x3F519857u; memcpy(&beta,  &bb, 4); }  // e^-0.2f

    zpad<34, 129><<<2560, 256, 0, stream>>>((uint32_t*)s1p);
    zpad3<<<40, 256, 0, stream>>>((uint32_t*)s2pt);
    wtrans<<<288, 256, 0, stream>>>(w2, wt2, 576, 128);
    wtrans3b<<<1152, 256, 0, stream>>>(w3, wt3b);
    conv1_lif<<<dim3(16, 128, 4), 256, 0, stream>>>(x, w1, b1, s1p, alpha, beta);
    // L2 conv: 2 chains x 40 frames; 16co x 4px; grid (4,8,80)=2560 blocks
    conv2_chains<<<dim3(4, 8, 80), 256, 0, stream>>>(s1p, wt2, p2a, p2b);
    lif_s2_t<<<dim3(512, 1, 4), 256, 0, stream>>>(p2a, p2b, b2, s2pt, alpha, beta);
    // L3 conv: MFMA; grid (8 h-groups, 4 co-groups, 40 frames) = 1280 blocks
    conv3_mfma<<<dim3(8, 4, 40), 256, 0, stream>>>(s2pt, wt3b, p3);
    lif_mean1<<<dim3(1, 256, 4), 256, 0, stream>>>(p3, b3, pooled, alpha, beta);
    det_conv<<<dim3(16, 4, 4), 256, 0, stream>>>(pooled, wd, bd, out);
}

// Round 2
// 660.018 us; speedup vs baseline: 1.1714x; 1.1714x over previous
//
#include <hip/hip_runtime.h>
#include <stdint.h>
#include <string.h>
#include <cmath>

// SpikingYOLO round 19: conv3 MFMA v2 — LDS-staged B (double-buffered,
// counted vmcnt, raw barriers), waves split by co (no cross-wave B dup),
// M=64 px per wave (R=4 reuse per B fragment). Weights pre-generated in the
// exact global_load_lds staging layout [cob][tap][term][16KB fragment-major
// tile] with the u8->bf16 perm folded in. Layers 1-2 bit-identical to R18.
// conv3 = same product set as R18 (3-term Dekker bf16 weight split, f32
// MFMA accum); only accumulation order permuted.

#define BB 4
#define TT 10

typedef short bf16x8 __attribute__((ext_vector_type(8)));
typedef float f32x4  __attribute__((ext_vector_type(4)));

// ------------------------------------------------ zero the pad borders (s1p)
template<int RS_DW, int NROWS>
__global__ __launch_bounds__(256) void zpad(uint32_t* __restrict__ buf) {
    const int plane = blockIdx.x;
    const int j = threadIdx.x;
    uint32_t* p = buf + (size_t)plane * (RS_DW * NROWS);
    if (j < NROWS) p[j * RS_DW] = 0u;                    // cols -4..-1 of every row
    const int k = j - NROWS;
    if (k >= 0 && k < RS_DW - 1) p[k + 1] = 0u;          // rest of top pad row (-1)
}

// ---------------- zero pads of s2pt: [40][65 rows][65 cols][128 ci] u8.
__global__ __launch_bounds__(256) void zpad3(uint32_t* __restrict__ buf) {
    uint32_t* p = buf + (size_t)blockIdx.x * 135200u;
    for (int i = threadIdx.x; i < 4160; i += 256) {
        if (i < 2080) p[i] = 0u;                          // row 0
        else { int j = i - 2080; p[(j >> 5) * 2080 + (j & 31)] = 0u; }  // col 0
    }
}

// ---------------------------------------------------------------- conv1+LIF
__global__ __launch_bounds__(256) void conv1_lif(
    const float* __restrict__ x,    // [4,2,128,128,10]
    const float* __restrict__ w1,   // [64,2,3,3]
    const float* __restrict__ b1,   // [64]
    uint8_t* __restrict__ s1p,      // padded [40*64][129][136]
    float alpha, float beta)
{
    __shared__ float xs[2][3][10][10];   // [ci][kh][wi][t]
    __shared__ float wsh[18][64];        // [tap][co]
    const int tid = threadIdx.x;
    const int b = blockIdx.z, h = blockIdx.y, w0 = blockIdx.x * 8;

    for (int i = tid; i < 1152; i += 256) {
        int co = i & 63, tap = i >> 6;
        wsh[tap][co] = w1[co * 18 + tap];
    }
    for (int i = tid; i < 600; i += 256) {
        int t = i % 10; int rest = i / 10;
        int wi = rest % 10; rest /= 10;
        int kh = rest % 3; int ci = rest / 3;
        int hh = h - 1 + kh, ww = w0 - 1 + wi;
        float v = 0.f;
        if (hh >= 0 && hh < 128 && ww >= 0 && ww < 128)
            v = x[(((b * 2 + ci) * 128 + hh) * 128 + ww) * 10 + t];
        xs[ci][kh][wi][t] = v;
    }
    __syncthreads();

    const int px  = tid & 7;
    const int cog = (tid >> 3) * 2;
    float acc[2][10];
#pragma unroll
    for (int c = 0; c < 2; ++c)
#pragma unroll
        for (int t = 0; t < 10; ++t) acc[c][t] = 0.f;

#pragma unroll
    for (int tap = 0; tap < 18; ++tap) {
        const int ci = tap / 9, kh = (tap % 9) / 3, kw = tap % 3;
        float2 wv = *(const float2*)&wsh[tap][cog];
#pragma unroll
        for (int t = 0; t < 10; ++t) {
            float xv = xs[ci][kh][px + kw][t];
            acc[0][t] = __fmaf_rn(wv.x, xv, acc[0][t]);
            acc[1][t] = __fmaf_rn(wv.y, xv, acc[1][t]);
        }
    }
#pragma unroll
    for (int c = 0; c < 2; ++c) {
        const float bv = b1[cog + c];
        float syn = 0.f, mem = 0.f;
#pragma unroll
        for (int t = 0; t < 10; ++t) {
            float cur = __fadd_rn(acc[c][t], bv);
            syn = __fadd_rn(__fmul_rn(beta, syn), cur);
            mem = __fadd_rn(__fmul_rn(alpha, mem), syn);
            float sp = (mem >= 1.0f) ? 1.0f : 0.0f;
            mem = __fsub_rn(mem, sp);
            s1p[(uint32_t)((t * BB + b) * 64 + (cog + c)) * 17544u
                + (h + 1) * 136 + (w0 + px + 4)] = (uint8_t)sp;
        }
    }
}

// --------------------------------------------------- weight transpose (wt2)
__global__ __launch_bounds__(256) void wtrans(
    const float* __restrict__ w, float* __restrict__ wt, int K, int COUT)
{
    int i = blockIdx.x * 256 + threadIdx.x;
    if (i < K * COUT) {
        int k = i / COUT, co = i - k * COUT;
        wt[i] = w[co * K + k];
    }
}

// --------- w3 -> 3-term bf16 split in conv3's LDS staging layout:
// [cob(4)][tap(9)][term(3)][tile 16KB]; tile byte o = ((wq*4+c)*64+lane)*16
// + e*2 holds weight(co = cob*64+wq*16+(lane&15), ci = c*32+(lane>>4)*8+sig(e))
// where sig swaps 1<->2, 5<->6 (u8->bf16 convert order compensation).
__global__ __launch_bounds__(256) void wtrans3c(
    const float* __restrict__ w3, unsigned short* __restrict__ wtb)
{
    int i = blockIdx.x * 256 + threadIdx.x;
    if (i >= 294912) return;                 // 256*128*9
    int co  = i / 1152;
    int rem = i - co * 1152;
    int ci  = rem / 9;
    int tap = rem - ci * 9;                  // kh*3+kw
    float w = w3[i];                         // [co][ci][kh][kw]
    uint32_t uw  = __float_as_uint(w);
    uint32_t h16 = (uw + 0x7FFFu + ((uw >> 16) & 1u)) >> 16;   // RNE bf16
    float hf = __uint_as_float(h16 << 16);
    float r1 = w - hf;                                          // exact
    uint32_t ur1 = __float_as_uint(r1);
    uint32_t m16 = (ur1 + 0x7FFFu + ((ur1 >> 16) & 1u)) >> 16;
    float mf = __uint_as_float(m16 << 16);
    float r2 = r1 - mf;                                         // exact
    uint32_t ur2 = __float_as_uint(r2);
    uint32_t l16 = (ur2 + 0x7FFFu + ((ur2 >> 16) & 1u)) >> 16;

    int cobi = co >> 6, coL = co & 63;
    int wq = coL >> 4, l15 = coL & 15;
    int cc = ci >> 5, r5 = ci & 31;
    int gg = r5 >> 3, e = r5 & 7;
    if ((e & 3) == 1 || (e & 3) == 2) e ^= 3;                   // perm fold
    int lane = gg * 16 + l15;
    size_t base = (size_t)((cobi * 9 + tap) * 3) * 8192
                + (size_t)(((wq * 4 + cc) * 64 + lane) * 8 + e);
    wtb[base]           = (unsigned short)h16;
    wtb[base + 8192]    = (unsigned short)m16;   // term stride = 16KB
    wtb[base + 16384]   = (unsigned short)l16;
}

// -------------------------------- per-ci conv taps, 16co x 4px (u8 input)
template<int COUT, int PLANE, int KHB, int KHE>
__device__ __forceinline__ void conv_ci16(
    int ci, const uint8_t* __restrict__ fb, const float* __restrict__ wt,
    int cob, const int off[3], float part[64])
{
    const uint8_t* p = fb + (uint32_t)ci * PLANE;
    uint32_t d0[3], d1[3], d2[3];
#pragma unroll
    for (int kh = KHB; kh < KHE; ++kh) {
        const uint8_t* q = p + off[kh];
        uint2 v = *(const uint2*)q;
        d0[kh] = v.x; d1[kh] = v.y;
        d2[kh] = *(const uint32_t*)(q + 8);
    }
#pragma unroll
    for (int kh = KHB; kh < KHE; ++kh) {
        float sv[9];
        sv[0] = (float)(d0[kh] >> 24);
        sv[1] = (float)(d1[kh] & 0xffu);
        sv[2] = (float)((d1[kh] >> 8) & 0xffu);
        sv[3] = (float)((d1[kh] >> 16) & 0xffu);
        sv[4] = (float)(d1[kh] >> 24);
        sv[5] = (float)(d2[kh] & 0xffu);
        sv[6] = (float)((d2[kh] >> 8) & 0xffu);
        sv[7] = (float)((d2[kh] >> 16) & 0xffu);
        sv[8] = (float)(d2[kh] >> 24);
#pragma unroll
        for (int kw = 0; kw < 3; ++kw) {
            const float* wp = wt + (ci * 9 + kh * 3 + kw) * COUT + cob;
#pragma unroll
            for (int co = 0; co < 16; ++co) {
                const float wv = wp[co];
#pragma unroll
                for (int j = 0; j < 4; ++j)
                    part[co * 4 + j] = __fmaf_rn(wv, sv[2 * j + kw], part[co * 4 + j]);
            }
        }
    }
}

// ------------------- L2 conv, chain-split (numerics identical to R17/R18).
__global__ __launch_bounds__(256) void conv2_chains(
    const uint8_t* __restrict__ sin,   // s1p padded [40*64][129][136]
    const float* __restrict__ wt,      // [576][128]
    float* __restrict__ p0, float* __restrict__ p1)
{
    const int tid = threadIdx.x;
    const int zc  = blockIdx.z / 40;
    const int f   = blockIdx.z - zc * 40;
    const int w4  = tid & 15;            // 16 w-groups x 4px = 64 cols
    const int hh  = blockIdx.x * 16 + (tid >> 4);
    const int cob = blockIdx.y * 16;

    const uint8_t* fb = sin + (size_t)f * 64 * 17544;
    int off[3];
#pragma unroll
    for (int kh = 0; kh < 3; ++kh) off[kh] = (2 * hh + kh) * 136 + 8 * w4;

    float part[64];
#pragma unroll
    for (int n = 0; n < 64; ++n) part[n] = 0.f;

    float* outp;
    if (zc == 0) {
        for (int ci = 0; ci < 42; ++ci)
            conv_ci16<128,17544,0,3>(ci, fb, wt, cob, off, part);
        conv_ci16<128,17544,0,2>(42, fb, wt, cob, off, part);
        outp = p0;
    } else {
        conv_ci16<128,17544,2,3>(42, fb, wt, cob, off, part);
        for (int ci = 43; ci < 64; ++ci)
            conv_ci16<128,17544,0,3>(ci, fb, wt, cob, off, part);
        outp = p1;
    }

#pragma unroll
    for (int j = 0; j < 4; ++j) {
        float* op = &outp[((uint32_t)f * 4096u + (uint32_t)(hh * 64 + 4 * w4 + j)) * 128u + cob];
#pragma unroll
        for (int a = 0; a < 4; ++a)
            *(float4*)(op + 4 * a) = make_float4(part[(4*a+0)*4+j], part[(4*a+1)*4+j],
                                                 part[(4*a+2)*4+j], part[(4*a+3)*4+j]);
    }
}

// ---------------------- LIF from 2 chain partials -> u8 spikes, layer 2.
__global__ __launch_bounds__(256) void lif_s2_t(
    const float* __restrict__ pa, const float* __restrict__ pb,
    const float* __restrict__ bias,
    uint8_t* __restrict__ s2pt, float alpha, float beta)
{
    const int tid = threadIdx.x;
    const int b   = blockIdx.z;
    const int px  = blockIdx.x * 8 + (tid >> 5);
    const int co0 = (tid & 31) * 4;
    const int h = px >> 6, w = px & 63;
    float4 bv = *(const float4*)&bias[co0];
    const float bva[4] = {bv.x, bv.y, bv.z, bv.w};
    float syn[4] = {0.f,0.f,0.f,0.f}, mem[4] = {0.f,0.f,0.f,0.f};
    uint8_t* sp = s2pt + (uint32_t)(h + 1) * 8320u + (uint32_t)(w + 1) * 128u + co0;
    for (int t = 0; t < TT; ++t) {
        const int f = t * BB + b;
        const uint32_t idx = ((uint32_t)f * 4096u + px) * 128u + co0;
        float4 A = *(const float4*)&pa[idx];
        float4 B = *(const float4*)&pb[idx];
        const float va[4] = {A.x, A.y, A.z, A.w};
        const float vb[4] = {B.x, B.y, B.z, B.w};
        uint32_t pk = 0;
#pragma unroll
        for (int j = 0; j < 4; ++j) {
            float conv = __fadd_rn(__fadd_rn(0.0f, va[j]), vb[j]);
            float c = __fadd_rn(conv, bva[j]);
            syn[j] = __fadd_rn(__fmul_rn(beta, syn[j]), c);
            mem[j] = __fadd_rn(__fmul_rn(alpha, mem[j]), syn[j]);
            bool sc = (mem[j] >= 1.0f);
            mem[j] = __fsub_rn(mem[j], sc ? 1.0f : 0.0f);
            pk |= (sc ? 1u : 0u) << (j * 8);
        }
        *(uint32_t*)(sp + (uint32_t)f * 540800u) = pk;
    }
}

// ------------------- L3 conv via MFMA, LDS-staged B, double-buffered.
// Block: 4 waves; covers 64 px (2 output rows x 32) x 64 co. Wave w owns co
// quarter [cob + w*16). Per (tap,term) tile: stage 16KB B to LDS (4x
// global_load_lds width-16 per thread, linear copy), each wave ds_read_b128
// its 4 chunk-fragments, 16 MFMAs. A-spikes prefetched one tap ahead
// (16 dwordx2), converted once per tap, reused across 3 terms.
__global__ __launch_bounds__(256) void conv3_mfma2(
    const uint8_t* __restrict__ s2pt,       // [40][65][65][128] u8
    const unsigned short* __restrict__ wtb, // [4][9][3][16KB tiles]
    float* __restrict__ p3)                 // [40][256][32][32]
{
    __shared__ alignas(16) unsigned short Bs[2][8192];   // 2 x 16KB
    const int tid  = threadIdx.x;
    const int lane = tid & 63;
    const int wid  = tid >> 6;
    const int r = lane & 15, g = lane >> 4;
    const int f    = blockIdx.z;
    const int cobi = blockIdx.y;
    const int h0   = blockIdx.x * 2;

    const uint8_t* fbase = s2pt + (uint32_t)f * 540800u;
    const unsigned short* wt = wtb + (size_t)cobi * (27u * 8192u);

    f32x4 acc[4];
#pragma unroll
    for (int mt = 0; mt < 4; ++mt) acc[mt] = (f32x4){0.f, 0.f, 0.f, 0.f};

    uint2  araw[16];
    bf16x8 abf[16];

#define STAGE3(tt, s_) do {                                                    \
    _Pragma("unroll")                                                          \
    for (int p_ = 0; p_ < 4; ++p_) {                                           \
        const unsigned short* gs_ = wt + (size_t)(tt) * 8192                   \
                                    + p_ * 2048 + wid * 512 + lane * 8;        \
        unsigned short* ls_ = &Bs[s_][p_ * 2048 + wid * 512];                  \
        __builtin_amdgcn_global_load_lds(                                      \
            (const __attribute__((address_space(1))) unsigned int*)(const void*)gs_, \
            (__attribute__((address_space(3))) unsigned int*)(void*)ls_,       \
            16, 0, 0);                                                         \
    } } while (0)

#define LOADA3(tap_) do {                                                      \
    const int kh_ = (tap_) / 3, kw_ = (tap_) - kh_ * 3;                        \
    _Pragma("unroll")                                                          \
    for (int mt_ = 0; mt_ < 4; ++mt_) {                                        \
        const uint8_t* rp_ = fbase                                             \
            + (uint32_t)(2 * h0 + 2 * (mt_ >> 1) + kh_) * 8320u                \
            + (uint32_t)(2 * ((mt_ & 1) * 16 + r) + kw_) * 128u + g * 8u;      \
        _Pragma("unroll")                                                      \
        for (int c_ = 0; c_ < 4; ++c_)                                         \
            araw[mt_ * 4 + c_] = *(const uint2*)(rp_ + c_ * 32);               \
    } } while (0)

#define CVTA3() do {                                                           \
    _Pragma("unroll")                                                          \
    for (int i_ = 0; i_ < 16; ++i_) {                                          \
        union { uint32_t u[4]; bf16x8 v; } tu_;                                \
        tu_.u[0] = (araw[i_].x & 0x00FF00FFu) * 0x3F80u;                       \
        tu_.u[1] = ((araw[i_].x >> 8) & 0x00FF00FFu) * 0x3F80u;                \
        tu_.u[2] = (araw[i_].y & 0x00FF00FFu) * 0x3F80u;                       \
        tu_.u[3] = ((araw[i_].y >> 8) & 0x00FF00FFu) * 0x3F80u;                \
        abf[i_] = tu_.v;                                                       \
    } } while (0)

    LOADA3(0);          // A(tap 0): 16 vm ops (oldest)
    STAGE3(0, 0);       // stage tile 0 -> buf 0
    int sel = 0;

    for (int tap = 0; tap < 9; ++tap) {
#pragma unroll
        for (int term = 0; term < 3; ++term) {
            const int t = tap * 3 + term;
            if (t < 26) STAGE3(t + 1, sel ^ 1);
            __builtin_amdgcn_sched_barrier(0);
            // ensure stage(t) (and everything older: A(cur tap)) complete;
            // leave only the 4 newest (stage(t+1)) in flight.
            if (t < 26) asm volatile("s_waitcnt vmcnt(4)" ::: "memory");
            else        asm volatile("s_waitcnt vmcnt(0)" ::: "memory");
            __builtin_amdgcn_sched_barrier(0);
            __builtin_amdgcn_s_barrier();          // tile t visible to all waves
            if (term == 0) CVTA3();                // A(tap) raw -> bf16 frags
#pragma unroll
            for (int c = 0; c < 4; ++c) {
                bf16x8 b = *(const bf16x8*)&Bs[sel][(wid * 4 + c) * 512 + lane * 8];
                acc[0] = __builtin_amdgcn_mfma_f32_16x16x32_bf16(abf[c],      b, acc[0], 0, 0, 0);
                acc[1] = __builtin_amdgcn_mfma_f32_16x16x32_bf16(abf[4 + c],  b, acc[1], 0, 0, 0);
                acc[2] = __builtin_amdgcn_mfma_f32_16x16x32_bf16(abf[8 + c],  b, acc[2], 0, 0, 0);
                acc[3] = __builtin_amdgcn_mfma_f32_16x16x32_bf16(abf[12 + c], b, acc[3], 0, 0, 0);
            }
            if (term == 2 && tap < 8) LOADA3(tap + 1);   // prefetch next tap's A
            __builtin_amdgcn_sched_barrier(0);
            __builtin_amdgcn_s_barrier();          // all reads of buf done
            sel ^= 1;
        }
    }

    const int cob = cobi * 64;
#pragma unroll
    for (int mt = 0; mt < 4; ++mt) {
        const int hh = h0 + (mt >> 1);
        const int wc = (mt & 1) * 16 + g * 4;
        *(f32x4*)&p3[((uint32_t)(f * 256 + cob + wid * 16 + r) * 32u + hh) * 32u + wc] = acc[mt];
    }
#undef STAGE3
#undef LOADA3
#undef CVTA3
}

// ---------------------- LIF + time-mean from the single conv3 buffer
__global__ __launch_bounds__(256) void lif_mean1(
    const float* __restrict__ p3, const float* __restrict__ bias,
    float* __restrict__ pooled, float alpha, float beta)
{
    const int px = (blockIdx.x * 256 + threadIdx.x) * 4;
    const int co = blockIdx.y;
    const int b  = blockIdx.z;
    const float bv = bias[co];
    float syn[4] = {0.f,0.f,0.f,0.f}, mem[4] = {0.f,0.f,0.f,0.f};
    float sum[4] = {0.f,0.f,0.f,0.f};
    for (int t = 0; t < TT; ++t) {
        const int idx = ((t * BB + b) * 256 + co) * 1024 + px;
        float4 a = *(const float4*)&p3[idx];
        const float va[4] = {a.x, a.y, a.z, a.w};
#pragma unroll
        for (int j = 0; j < 4; ++j) {
            float cu = __fadd_rn(va[j], bv);
            syn[j] = __fadd_rn(__fmul_rn(beta, syn[j]), cu);
            mem[j] = __fadd_rn(__fmul_rn(alpha, mem[j]), syn[j]);
            bool sc = (mem[j] >= 1.0f);
            float sp = sc ? 1.0f : 0.0f;
            mem[j] = __fsub_rn(mem[j], sp);
            sum[j] = __fadd_rn(sum[j], sp);
        }
    }
    *(float4*)&pooled[(b * 256 + co) * 1024 + px] =
        make_float4(sum[0] / 10.0f, sum[1] / 10.0f, sum[2] / 10.0f, sum[3] / 10.0f);
}

// ------------------------------------------------------------------ det 1x1
__global__ __launch_bounds__(256) void det_conv(
    const float* __restrict__ pooled, // [4,256,1024]
    const float* __restrict__ wd,     // [255,256]
    const float* __restrict__ bd,     // [255]
    float* __restrict__ out)          // [4,255,1024]
{
    __shared__ float wtl[16][64];
    __shared__ float ps[16][64];
    const int tid = threadIdx.x;
    const int b = blockIdx.z;
    const int o_base = blockIdx.y * 64;
    const int px_base = blockIdx.x * 64;
    const int o_off = (tid >> 4) * 4;
    const int px_off = (tid & 15) * 4;
    float acc[4][4];
#pragma unroll
    for (int c = 0; c < 4; ++c) {
        int o = o_base + o_off + c;
        float bv = (o < 255) ? bd[o] : 0.f;
#pragma unroll
        for (int j = 0; j < 4; ++j) acc[c][j] = bv;
    }
    for (int cc = 0; cc < 16; ++cc) {
        for (int k = tid; k < 1024; k += 256) {
            int o = k & 63, ci = k >> 6;
            wtl[ci][o] = (o_base + o < 255) ? wd[(o_base + o) * 256 + cc * 16 + ci] : 0.f;
            ps[ci][o] = pooled[(b * 256 + cc * 16 + ci) * 1024 + px_base + o];
        }
        __syncthreads();
#pragma unroll
        for (int ci = 0; ci < 16; ++ci) {
            float4 wv = *(const float4*)&wtl[ci][o_off];
            float4 sv = *(const float4*)&ps[ci][px_off];
            acc[0][0] += wv.x * sv.x; acc[0][1] += wv.x * sv.y;
            acc[0][2] += wv.x * sv.z; acc[0][3] += wv.x * sv.w;
            acc[1][0] += wv.y * sv.x; acc[1][1] += wv.y * sv.y;
            acc[1][2] += wv.y * sv.z; acc[1][3] += wv.y * sv.w;
            acc[2][0] += wv.z * sv.x; acc[2][1] += wv.z * sv.y;
            acc[2][2] += wv.z * sv.z; acc[2][3] += wv.z * sv.w;
            acc[3][0] += wv.w * sv.x; acc[3][1] += wv.w * sv.y;
            acc[3][2] += wv.w * sv.z; acc[3][3] += wv.w * sv.w;
        }
        __syncthreads();
    }
#pragma unroll
    for (int c = 0; c < 4; ++c) {
        int o = o_base + o_off + c;
        if (o < 255)
            *(float4*)&out[(b * 255 + o) * 1024 + px_base + px_off] =
                make_float4(acc[c][0], acc[c][1], acc[c][2], acc[c][3]);
    }
}

extern "C" void kernel_launch(void* const* d_in, const int* in_sizes, int n_in,
                              void* d_out, int out_size, void* d_ws, size_t ws_size,
                              hipStream_t stream) {
    const float* x  = (const float*)d_in[0];
    const float* w1 = (const float*)d_in[1];
    const float* b1 = (const float*)d_in[2];
    const float* w2 = (const float*)d_in[3];
    const float* b2 = (const float*)d_in[4];
    const float* w3 = (const float*)d_in[5];
    const float* b3 = (const float*)d_in[6];
    const float* wd = (const float*)d_in[7];
    const float* bd = (const float*)d_in[8];
    float* out = (float*)d_out;

    // ws layout with aliasing (lifetimes; ~236.4 MB):
    //   s1p  u8 [2560][17544]   @ 256          (44,912,640)  conv1 -> conv2
    //   p3   f32 [40*256*1024]  @ 256          (41,943,040)  conv3 -> lif_mean1 (overlays s1p)
    //   p2a  f32 [40][4096][128]@ 44,912,896   (83,886,080)  conv2 -> lif_s2_t
    //   pooled f32              @ 44,912,896   (4,194,304)   lif_mean1 -> det (overlays p2a)
    //   p2b  f32                @ 128,798,976  (83,886,080)  conv2 -> lif_s2_t
    //   s2pt u8 [40][65][65][128]@212,685,056  (21,632,000)  lif_s2_t -> conv3
    //   wt2  f32 [576][128]     @ 234,317,056  (294,912)
    //   wt3b bf16 [4][27][8192] @ 234,611,968  (1,769,472)   end 236,381,440
    uint8_t* wsb = (uint8_t*)d_ws;
    uint8_t* s1p    = wsb + 256;
    float*   p3     = (float*)(wsb + 256);
    float*   p2a    = (float*)(wsb + 44912896u);
    float*   pooled = (float*)(wsb + 44912896u);
    float*   p2b    = (float*)(wsb + 128798976u);
    uint8_t* s2pt   = wsb + 212685056u;
    float*   wt2    = (float*)(wsb + 234317056u);
    unsigned short* wt3b = (unsigned short*)(wsb + 234611968u);

    float alpha, beta;
    { uint32_t ab = 0x3F7383C6u; memcpy(&alpha, &ab, 4); }  // e^-0.05f
    { uint32_t bb = 0x3F519857u; memcpy(&beta,  &bb, 4); }  // e^-0.2f

    zpad<34, 129><<<2560, 256, 0, stream>>>((uint32_t*)s1p);
    zpad3<<<40, 256, 0, stream>>>((uint32_t*)s2pt);
    wtrans<<<288, 256, 0, stream>>>(w2, wt2, 576, 128);
    wtrans3c<<<1152, 256, 0, stream>>>(w3, wt3b);
    conv1_lif<<<dim3(16, 128, 4), 256, 0, stream>>>(x, w1, b1, s1p, alpha, beta);
    // L2 conv: 2 chains x 40 frames; 16co x 4px; grid (4,8,80)=2560 blocks
    conv2_chains<<<dim3(4, 8, 80), 256, 0, stream>>>(s1p, wt2, p2a, p2b);
    lif_s2_t<<<dim3(512, 1, 4), 256, 0, stream>>>(p2a, p2b, b2, s2pt, alpha, beta);
    // L3 conv: MFMA v2; grid (16 row-pairs, 4 co-groups, 40 frames)
    conv3_mfma2<<<dim3(16, 4, 40), 256, 0, stream>>>(s2pt, wt3b, p3);
    lif_mean1<<<dim3(1, 256, 4), 256, 0, stream>>>(p3, b3, pooled, alpha, beta);
    det_conv<<<dim3(16, 4, 4), 256, 0, stream>>>(pooled, wd, bd, out);
}

// Round 3
// 595.359 us; speedup vs baseline: 1.2986x; 1.1086x over previous
//
#include <hip/hip_runtime.h>
#include <stdint.h>
#include <string.h>
#include <cmath>

// SpikingYOLO round 20: BOTH big convs on MFMA with a shared pipelined
// template: bf16 spike planes (no u8->bf16 VALU, A = direct dwordx4 loads),
// ring-3 LDS weight staging (2-tile latency coverage, counted vmcnt never 0
// until tail), A-fragment double-buffer alternated per tap (compile-time).
// conv2: weights as X operand -> f32x4 px-major stores, single partial
// buffer (write traffic halved). conv3 accumulation order identical to R19.
// conv1 LIF ops bit-identical; layer-2 conv now 3-term bf16 Dekker MFMA
// (same transform that produced zero flips at layer 3 in R18).

#define BB 4
#define TT 10

typedef short bf16x8 __attribute__((ext_vector_type(8)));
typedef float f32x4  __attribute__((ext_vector_type(4)));

// s1pt: [40][129 rows][130 cols][64 ci] bf16 (row -1.., col -1..): row stride
//   8320 elems, plane 1,073,280 elems (2,146,560 B)
// s2pt: [40][65][65][128] bf16: row stride 8320 elems, plane 540,800 elems

// ---------------- zero pads of s1pt (u32 view): plane 536,640 u32,
// row stride 4160 u32; zero row 0 (4160) + col 0 (32 u32) of rows 0..128.
__global__ __launch_bounds__(256) void zpad1t(uint32_t* __restrict__ buf) {
    uint32_t* p = buf + (size_t)blockIdx.x * 536640u;
    for (int i = threadIdx.x; i < 8288; i += 256) {
        if (i < 4160) p[i] = 0u;
        else { int j = i - 4160; p[(j >> 5) * 4160 + (j & 31)] = 0u; }
    }
}

// ---------------- zero pads of s2pt (u32 view): plane 270,400 u32,
// row stride 4160 u32; zero row 0 (4160) + col 0 (64 u32) of rows 0..64.
__global__ __launch_bounds__(256) void zpad3b(uint32_t* __restrict__ buf) {
    uint32_t* p = buf + (size_t)blockIdx.x * 270400u;
    for (int i = threadIdx.x; i < 8320; i += 256) {
        if (i < 4160) p[i] = 0u;
        else { int j = i - 4160; p[(j >> 6) * 4160 + (j & 63)] = 0u; }
    }
}

// ---------------------------------------------------------------- conv1+LIF
// LIF arithmetic bit-identical to R9..R19; stores bf16 spike (0x3F80 / 0).
__global__ __launch_bounds__(256) void conv1_lif(
    const float* __restrict__ x,    // [4,2,128,128,10]
    const float* __restrict__ w1,   // [64,2,3,3]
    const float* __restrict__ b1,   // [64]
    unsigned short* __restrict__ s1pt,  // [40][129][130][64] bf16
    float alpha, float beta)
{
    __shared__ float xs[2][3][10][10];   // [ci][kh][wi][t]
    __shared__ float wsh[18][64];        // [tap][co]
    const int tid = threadIdx.x;
    const int b = blockIdx.z, h = blockIdx.y, w0 = blockIdx.x * 8;

    for (int i = tid; i < 1152; i += 256) {
        int co = i & 63, tap = i >> 6;
        wsh[tap][co] = w1[co * 18 + tap];
    }
    for (int i = tid; i < 600; i += 256) {
        int t = i % 10; int rest = i / 10;
        int wi = rest % 10; rest /= 10;
        int kh = rest % 3; int ci = rest / 3;
        int hh = h - 1 + kh, ww = w0 - 1 + wi;
        float v = 0.f;
        if (hh >= 0 && hh < 128 && ww >= 0 && ww < 128)
            v = x[(((b * 2 + ci) * 128 + hh) * 128 + ww) * 10 + t];
        xs[ci][kh][wi][t] = v;
    }
    __syncthreads();

    const int px  = tid & 7;
    const int cog = (tid >> 3) * 2;
    float acc[2][10];
#pragma unroll
    for (int c = 0; c < 2; ++c)
#pragma unroll
        for (int t = 0; t < 10; ++t) acc[c][t] = 0.f;

#pragma unroll
    for (int tap = 0; tap < 18; ++tap) {
        const int ci = tap / 9, kh = (tap % 9) / 3, kw = tap % 3;
        float2 wv = *(const float2*)&wsh[tap][cog];
#pragma unroll
        for (int t = 0; t < 10; ++t) {
            float xv = xs[ci][kh][px + kw][t];
            acc[0][t] = __fmaf_rn(wv.x, xv, acc[0][t]);
            acc[1][t] = __fmaf_rn(wv.y, xv, acc[1][t]);
        }
    }
#pragma unroll
    for (int c = 0; c < 2; ++c) {
        const float bv = b1[cog + c];
        float syn = 0.f, mem = 0.f;
#pragma unroll
        for (int t = 0; t < 10; ++t) {
            float cur = __fadd_rn(acc[c][t], bv);
            syn = __fadd_rn(__fmul_rn(beta, syn), cur);
            mem = __fadd_rn(__fmul_rn(alpha, mem), syn);
            bool sc = (mem >= 1.0f);
            float sp = sc ? 1.0f : 0.0f;
            mem = __fsub_rn(mem, sp);
            s1pt[(uint32_t)(t * BB + b) * 1073280u
                 + (h + 1) * 8320u + (w0 + px + 1) * 64u + (cog + c)] =
                sc ? (unsigned short)0x3F80 : (unsigned short)0;
        }
    }
}

// --------- w2 -> 3-term bf16 split, staging layout [cobi(2)][tap(9)][term(3)]
// [4096-elem tile]; tile elem = ((wid*2+c)*64 + (g*16+l15))*8 + e holds
// weight(co = cobi*64+wid*16+l15, ci = c*32+g*8+e).
__global__ __launch_bounds__(256) void wtrans2c(
    const float* __restrict__ w2, unsigned short* __restrict__ wtb)
{
    int i = blockIdx.x * 256 + threadIdx.x;
    if (i >= 73728) return;                  // 128*64*9
    int co  = i / 576;
    int rem = i - co * 576;
    int ci  = rem / 9;
    int tap = rem - ci * 9;
    float w = w2[i];                         // [co][ci][kh][kw]
    uint32_t uw  = __float_as_uint(w);
    uint32_t h16 = (uw + 0x7FFFu + ((uw >> 16) & 1u)) >> 16;   // RNE bf16
    float hf = __uint_as_float(h16 << 16);
    float r1 = w - hf;
    uint32_t ur1 = __float_as_uint(r1);
    uint32_t m16 = (ur1 + 0x7FFFu + ((ur1 >> 16) & 1u)) >> 16;
    float mf = __uint_as_float(m16 << 16);
    float r2 = r1 - mf;
    uint32_t ur2 = __float_as_uint(r2);
    uint32_t l16 = (ur2 + 0x7FFFu + ((ur2 >> 16) & 1u)) >> 16;

    int cobi = co >> 6, coL = co & 63;
    int wid = coL >> 4, l15 = coL & 15;
    int c = ci >> 5, r5 = ci & 31;
    int g = r5 >> 3, e = r5 & 7;
    size_t base = (size_t)(cobi * 27 + tap * 3) * 4096
                + (size_t)(((wid * 2 + c) * 64 + (g * 16 + l15)) * 8 + e);
    wtb[base]        = (unsigned short)h16;
    wtb[base + 4096] = (unsigned short)m16;
    wtb[base + 8192] = (unsigned short)l16;
}

// --------- w3 -> 3-term bf16 split, layout [cobi(4)][tap(9)][term(3)]
// [8192-elem tile]; tile elem = ((wq*4+cc)*64 + (g*16+l15))*8 + e holds
// weight(co = cobi*64+wq*16+l15, ci = cc*32+g*8+e). Natural e order.
__global__ __launch_bounds__(256) void wtrans3c(
    const float* __restrict__ w3, unsigned short* __restrict__ wtb)
{
    int i = blockIdx.x * 256 + threadIdx.x;
    if (i >= 294912) return;                 // 256*128*9
    int co  = i / 1152;
    int rem = i - co * 1152;
    int ci  = rem / 9;
    int tap = rem - ci * 9;
    float w = w3[i];                         // [co][ci][kh][kw]
    uint32_t uw  = __float_as_uint(w);
    uint32_t h16 = (uw + 0x7FFFu + ((uw >> 16) & 1u)) >> 16;
    float hf = __uint_as_float(h16 << 16);
    float r1 = w - hf;
    uint32_t ur1 = __float_as_uint(r1);
    uint32_t m16 = (ur1 + 0x7FFFu + ((ur1 >> 16) & 1u)) >> 16;
    float mf = __uint_as_float(m16 << 16);
    float r2 = r1 - mf;
    uint32_t ur2 = __float_as_uint(r2);
    uint32_t l16 = (ur2 + 0x7FFFu + ((ur2 >> 16) & 1u)) >> 16;

    int cobi = co >> 6, coL = co & 63;
    int wq = coL >> 4, l15 = coL & 15;
    int cc = ci >> 5, r5 = ci & 31;
    int g = r5 >> 3, e = r5 & 7;
    size_t base = (size_t)(cobi * 27 + tap * 3) * 8192
                + (size_t)(((wq * 4 + cc) * 64 + (g * 16 + l15)) * 8 + e);
    wtb[base]         = (unsigned short)h16;
    wtb[base + 8192]  = (unsigned short)m16;
    wtb[base + 16384] = (unsigned short)l16;
}

#define VMCNT(n) do { __builtin_amdgcn_sched_barrier(0); \
    asm volatile("s_waitcnt vmcnt(" #n ")" ::: "memory"); \
    __builtin_amdgcn_sched_barrier(0); } while (0)
#define SB() __builtin_amdgcn_sched_barrier(0)
#define BAR() __builtin_amdgcn_s_barrier()

// ------------------- L2 conv via MFMA. Block: 4 waves (co-split 4x16) x
// 64 px (1 output row) x 64 co; grid (64, 2, 40). Weights X-operand, spikes
// Y-operand -> D lane = 4 consecutive co at one px -> f32x4 stores to
// [f][px][co]. Ring-3 LDS (3x8KB), A dbuf per tap. S=2, Na=8.
__global__ __launch_bounds__(256) void conv2_mfma(
    const unsigned short* __restrict__ s1pt,  // [40][129][130][64] bf16
    const unsigned short* __restrict__ wtb,   // [2][27][4096]
    float* __restrict__ p2)                   // [40][4096][128]
{
    __shared__ alignas(16) unsigned short Bs[3][4096];
    const int tid  = threadIdx.x;
    const int lane = tid & 63, wid = tid >> 6;
    const int r = lane & 15, g = lane >> 4;
    const int f = blockIdx.z, cobi = blockIdx.y;
    const int hb = blockIdx.x;                 // output row 0..63

    const unsigned short* fbase = s1pt + (uint32_t)f * 1073280u;
    const unsigned short* wt = wtb + (uint32_t)cobi * (27u * 4096u);

    f32x4 acc[4];
#pragma unroll
    for (int mt = 0; mt < 4; ++mt) acc[mt] = (f32x4){0.f, 0.f, 0.f, 0.f};
    bf16x8 aA[8], aB[8];

#define STAGE2(tt, ring_) do { _Pragma("unroll") \
    for (int p_ = 0; p_ < 2; ++p_) \
        __builtin_amdgcn_global_load_lds( \
            (const __attribute__((address_space(1))) unsigned int*)(const void*)(wt + (uint32_t)(tt) * 4096u + p_ * 2048 + tid * 8), \
            (__attribute__((address_space(3))) unsigned int*)(void*)(&Bs[ring_][p_ * 2048 + tid * 8]), \
            16, 0, 0); } while (0)

#define LOADA2(tap_, DST) do { \
    const int kh_ = (tap_) / 3, kw_ = (tap_) % 3; \
    _Pragma("unroll") \
    for (int mt_ = 0; mt_ < 4; ++mt_) { \
        const unsigned short* rp_ = fbase + (uint32_t)(2 * hb + kh_) * 8320u \
            + (uint32_t)(2 * (mt_ * 16 + r) + kw_) * 64u + (uint32_t)g * 8u; \
        _Pragma("unroll") \
        for (int c_ = 0; c_ < 2; ++c_) \
            DST[mt_ * 2 + c_] = *(const bf16x8*)(rp_ + c_ * 32); \
    } } while (0)

#define MTILE2(USE, ring_) do { _Pragma("unroll") \
    for (int c_ = 0; c_ < 2; ++c_) { \
        bf16x8 b_ = *(const bf16x8*)&Bs[ring_][(wid * 2 + c_) * 512 + lane * 8]; \
        acc[0] = __builtin_amdgcn_mfma_f32_16x16x32_bf16(b_, USE[0 + c_], acc[0], 0, 0, 0); \
        acc[1] = __builtin_amdgcn_mfma_f32_16x16x32_bf16(b_, USE[2 + c_], acc[1], 0, 0, 0); \
        acc[2] = __builtin_amdgcn_mfma_f32_16x16x32_bf16(b_, USE[4 + c_], acc[2], 0, 0, 0); \
        acc[3] = __builtin_amdgcn_mfma_f32_16x16x32_bf16(b_, USE[6 + c_], acc[3], 0, 0, 0); \
    } } while (0)

#define TAP2(tap_, USE, NXT) do { \
    STAGE2(3 * (tap_) + 2, 2); VMCNT(4); BAR(); \
    MTILE2(USE, 0); SB(); BAR(); \
    STAGE2(3 * (tap_) + 3, 0); VMCNT(4); BAR(); \
    MTILE2(USE, 1); LOADA2((tap_) + 1, NXT); SB(); BAR(); \
    STAGE2(3 * (tap_) + 4, 1); VMCNT(12); BAR(); \
    MTILE2(USE, 2); SB(); BAR(); \
} while (0)

    LOADA2(0, aA);
    STAGE2(0, 0); STAGE2(1, 1);

    TAP2(0, aA, aB); TAP2(1, aB, aA); TAP2(2, aA, aB); TAP2(3, aB, aA);
    TAP2(4, aA, aB); TAP2(5, aB, aA); TAP2(6, aA, aB); TAP2(7, aB, aA);
    // tap 8 tail (uses aA)
    STAGE2(26, 2); VMCNT(4); BAR();
    MTILE2(aA, 0); SB(); BAR();
    VMCNT(2); BAR();
    MTILE2(aA, 1); SB(); BAR();
    VMCNT(0); BAR();
    MTILE2(aA, 2);

#pragma unroll
    for (int mt = 0; mt < 4; ++mt)
        *(f32x4*)&p2[((uint32_t)f * 4096u + hb * 64 + mt * 16 + r) * 128u
                     + cobi * 64 + wid * 16 + g * 4] = acc[mt];
#undef STAGE2
#undef LOADA2
#undef MTILE2
#undef TAP2
}

// ---------------------- LIF layer 2: single MFMA partial -> bf16 spikes.
__global__ __launch_bounds__(256) void lif_s2_t(
    const float* __restrict__ pa, const float* __restrict__ bias,
    unsigned short* __restrict__ s2pt, float alpha, float beta)
{
    const int tid = threadIdx.x;
    const int b   = blockIdx.z;
    const int px  = blockIdx.x * 8 + (tid >> 5);
    const int co0 = (tid & 31) * 4;
    const int h = px >> 6, w = px & 63;
    float4 bv = *(const float4*)&bias[co0];
    const float bva[4] = {bv.x, bv.y, bv.z, bv.w};
    float syn[4] = {0.f,0.f,0.f,0.f}, mem[4] = {0.f,0.f,0.f,0.f};
    unsigned short* sp = s2pt + (uint32_t)(h + 1) * 8320u + (uint32_t)(w + 1) * 128u + co0;
    for (int t = 0; t < TT; ++t) {
        const int f = t * BB + b;
        const uint32_t idx = ((uint32_t)f * 4096u + px) * 128u + co0;
        float4 A = *(const float4*)&pa[idx];
        const float va[4] = {A.x, A.y, A.z, A.w};
        uint32_t pk[2] = {0u, 0u};
#pragma unroll
        for (int j = 0; j < 4; ++j) {
            float c = __fadd_rn(va[j], bva[j]);
            syn[j] = __fadd_rn(__fmul_rn(beta, syn[j]), c);
            mem[j] = __fadd_rn(__fmul_rn(alpha, mem[j]), syn[j]);
            bool sc = (mem[j] >= 1.0f);
            mem[j] = __fsub_rn(mem[j], sc ? 1.0f : 0.0f);
            pk[j >> 1] |= (sc ? 0x3F80u : 0u) << ((j & 1) * 16);
        }
        *(uint2*)(sp + (uint32_t)f * 540800u) = make_uint2(pk[0], pk[1]);
    }
}

// ------------------- L3 conv via MFMA. Block: 4 waves (co-split) x 64 px
// (2 output rows) x 64 co; grid (16, 4, 40). Spikes X, weights Y (R19
// orientation; accumulation order per output identical to R19).
// Ring-3 LDS (3x16KB), A dbuf. S=4, Na=16.
__global__ __launch_bounds__(256) void conv3_mfma3(
    const unsigned short* __restrict__ s2pt,  // [40][65][65][128] bf16
    const unsigned short* __restrict__ wtb,   // [4][27][8192]
    float* __restrict__ p3)                   // [40][256][32][32]
{
    __shared__ alignas(16) unsigned short Bs[3][8192];
    const int tid  = threadIdx.x;
    const int lane = tid & 63, wid = tid >> 6;
    const int r = lane & 15, g = lane >> 4;
    const int f = blockIdx.z, cobi = blockIdx.y;
    const int h0 = blockIdx.x * 2;

    const unsigned short* fbase = s2pt + (uint32_t)f * 540800u;
    const unsigned short* wt = wtb + (uint32_t)cobi * (27u * 8192u);

    f32x4 acc[4];
#pragma unroll
    for (int mt = 0; mt < 4; ++mt) acc[mt] = (f32x4){0.f, 0.f, 0.f, 0.f};
    bf16x8 aA[16], aB[16];

#define STAGE3(tt, ring_) do { _Pragma("unroll") \
    for (int p_ = 0; p_ < 4; ++p_) \
        __builtin_amdgcn_global_load_lds( \
            (const __attribute__((address_space(1))) unsigned int*)(const void*)(wt + (uint32_t)(tt) * 8192u + p_ * 2048 + tid * 8), \
            (__attribute__((address_space(3))) unsigned int*)(void*)(&Bs[ring_][p_ * 2048 + tid * 8]), \
            16, 0, 0); } while (0)

#define LOADA3(tap_, DST) do { \
    const int kh_ = (tap_) / 3, kw_ = (tap_) % 3; \
    _Pragma("unroll") \
    for (int mt_ = 0; mt_ < 4; ++mt_) { \
        const unsigned short* rp_ = fbase + (uint32_t)(2 * h0 + 2 * (mt_ >> 1) + kh_) * 8320u \
            + (uint32_t)(2 * ((mt_ & 1) * 16 + r) + kw_) * 128u + (uint32_t)g * 8u; \
        _Pragma("unroll") \
        for (int c_ = 0; c_ < 4; ++c_) \
            DST[mt_ * 4 + c_] = *(const bf16x8*)(rp_ + c_ * 32); \
    } } while (0)

#define MTILE3(USE, ring_) do { _Pragma("unroll") \
    for (int c_ = 0; c_ < 4; ++c_) { \
        bf16x8 b_ = *(const bf16x8*)&Bs[ring_][(wid * 4 + c_) * 512 + lane * 8]; \
        acc[0] = __builtin_amdgcn_mfma_f32_16x16x32_bf16(USE[0 + c_],  b_, acc[0], 0, 0, 0); \
        acc[1] = __builtin_amdgcn_mfma_f32_16x16x32_bf16(USE[4 + c_],  b_, acc[1], 0, 0, 0); \
        acc[2] = __builtin_amdgcn_mfma_f32_16x16x32_bf16(USE[8 + c_],  b_, acc[2], 0, 0, 0); \
        acc[3] = __builtin_amdgcn_mfma_f32_16x16x32_bf16(USE[12 + c_], b_, acc[3], 0, 0, 0); \
    } } while (0)

#define TAP3(tap_, USE, NXT) do { \
    STAGE3(3 * (tap_) + 2, 2); VMCNT(8); BAR(); \
    MTILE3(USE, 0); SB(); BAR(); \
    STAGE3(3 * (tap_) + 3, 0); VMCNT(8); BAR(); \
    MTILE3(USE, 1); LOADA3((tap_) + 1, NXT); SB(); BAR(); \
    STAGE3(3 * (tap_) + 4, 1); VMCNT(24); BAR(); \
    MTILE3(USE, 2); SB(); BAR(); \
} while (0)

    LOADA3(0, aA);
    STAGE3(0, 0); STAGE3(1, 1);

    TAP3(0, aA, aB); TAP3(1, aB, aA); TAP3(2, aA, aB); TAP3(3, aB, aA);
    TAP3(4, aA, aB); TAP3(5, aB, aA); TAP3(6, aA, aB); TAP3(7, aB, aA);
    // tap 8 tail (uses aA)
    STAGE3(26, 2); VMCNT(8); BAR();
    MTILE3(aA, 0); SB(); BAR();
    VMCNT(4); BAR();
    MTILE3(aA, 1); SB(); BAR();
    VMCNT(0); BAR();
    MTILE3(aA, 2);

    const int cob = cobi * 64;
#pragma unroll
    for (int mt = 0; mt < 4; ++mt) {
        const int hh = h0 + (mt >> 1);
        const int wc = (mt & 1) * 16 + g * 4;
        *(f32x4*)&p3[((uint32_t)(f * 256 + cob + wid * 16 + r) * 32u + hh) * 32u + wc] = acc[mt];
    }
#undef STAGE3
#undef LOADA3
#undef MTILE3
#undef TAP3
}

// ---------------------- LIF + time-mean from the single conv3 buffer
__global__ __launch_bounds__(256) void lif_mean1(
    const float* __restrict__ p3, const float* __restrict__ bias,
    float* __restrict__ pooled, float alpha, float beta)
{
    const int px = (blockIdx.x * 256 + threadIdx.x) * 4;
    const int co = blockIdx.y;
    const int b  = blockIdx.z;
    const float bv = bias[co];
    float syn[4] = {0.f,0.f,0.f,0.f}, mem[4] = {0.f,0.f,0.f,0.f};
    float sum[4] = {0.f,0.f,0.f,0.f};
    for (int t = 0; t < TT; ++t) {
        const int idx = ((t * BB + b) * 256 + co) * 1024 + px;
        float4 a = *(const float4*)&p3[idx];
        const float va[4] = {a.x, a.y, a.z, a.w};
#pragma unroll
        for (int j = 0; j < 4; ++j) {
            float cu = __fadd_rn(va[j], bv);
            syn[j] = __fadd_rn(__fmul_rn(beta, syn[j]), cu);
            mem[j] = __fadd_rn(__fmul_rn(alpha, mem[j]), syn[j]);
            bool sc = (mem[j] >= 1.0f);
            float sp = sc ? 1.0f : 0.0f;
            mem[j] = __fsub_rn(mem[j], sp);
            sum[j] = __fadd_rn(sum[j], sp);
        }
    }
    *(float4*)&pooled[(b * 256 + co) * 1024 + px] =
        make_float4(sum[0] / 10.0f, sum[1] / 10.0f, sum[2] / 10.0f, sum[3] / 10.0f);
}

// ------------------------------------------------------------------ det 1x1
__global__ __launch_bounds__(256) void det_conv(
    const float* __restrict__ pooled, // [4,256,1024]
    const float* __restrict__ wd,     // [255,256]
    const float* __restrict__ bd,     // [255]
    float* __restrict__ out)          // [4,255,1024]
{
    __shared__ float wtl[16][64];
    __shared__ float ps[16][64];
    const int tid = threadIdx.x;
    const int b = blockIdx.z;
    const int o_base = blockIdx.y * 64;
    const int px_base = blockIdx.x * 64;
    const int o_off = (tid >> 4) * 4;
    const int px_off = (tid & 15) * 4;
    float acc[4][4];
#pragma unroll
    for (int c = 0; c < 4; ++c) {
        int o = o_base + o_off + c;
        float bv = (o < 255) ? bd[o] : 0.f;
#pragma unroll
        for (int j = 0; j < 4; ++j) acc[c][j] = bv;
    }
    for (int cc = 0; cc < 16; ++cc) {
        for (int k = tid; k < 1024; k += 256) {
            int o = k & 63, ci = k >> 6;
            wtl[ci][o] = (o_base + o < 255) ? wd[(o_base + o) * 256 + cc * 16 + ci] : 0.f;
            ps[ci][o] = pooled[(b * 256 + cc * 16 + ci) * 1024 + px_base + o];
        }
        __syncthreads();
#pragma unroll
        for (int ci = 0; ci < 16; ++ci) {
            float4 wv = *(const float4*)&wtl[ci][o_off];
            float4 sv = *(const float4*)&ps[ci][px_off];
            acc[0][0] += wv.x * sv.x; acc[0][1] += wv.x * sv.y;
            acc[0][2] += wv.x * sv.z; acc[0][3] += wv.x * sv.w;
            acc[1][0] += wv.y * sv.x; acc[1][1] += wv.y * sv.y;
            acc[1][2] += wv.y * sv.z; acc[1][3] += wv.y * sv.w;
            acc[2][0] += wv.z * sv.x; acc[2][1] += wv.z * sv.y;
            acc[2][2] += wv.z * sv.z; acc[2][3] += wv.z * sv.w;
            acc[3][0] += wv.w * sv.x; acc[3][1] += wv.w * sv.y;
            acc[3][2] += wv.w * sv.z; acc[3][3] += wv.w * sv.w;
        }
        __syncthreads();
    }
#pragma unroll
    for (int c = 0; c < 4; ++c) {
        int o = o_base + o_off + c;
        if (o < 255)
            *(float4*)&out[(b * 255 + o) * 1024 + px_base + px_off] =
                make_float4(acc[c][0], acc[c][1], acc[c][2], acc[c][3]);
    }
}

extern "C" void kernel_launch(void* const* d_in, const int* in_sizes, int n_in,
                              void* d_out, int out_size, void* d_ws, size_t ws_size,
                              hipStream_t stream) {
    const float* x  = (const float*)d_in[0];
    const float* w1 = (const float*)d_in[1];
    const float* b1 = (const float*)d_in[2];
    const float* w2 = (const float*)d_in[3];
    const float* b2 = (const float*)d_in[4];
    const float* w3 = (const float*)d_in[5];
    const float* b3 = (const float*)d_in[6];
    const float* wd = (const float*)d_in[7];
    const float* bd = (const float*)d_in[8];
    float* out = (float*)d_out;

    // ws layout with aliasing (lifetimes; ~215.2 MB):
    //   s1pt u16 [40][129][130][64] @ 256         (85,862,400)  conv1 -> conv2
    //   p3   f32 [40*256*1024]      @ 256         (41,943,040)  conv3 -> lif_mean1 (overlays s1pt)
    //   p2   f32 [40][4096][128]    @ 85,862,656  (83,886,080)  conv2 -> lif_s2_t
    //   pooled f32                  @ 85,862,656  (4,194,304)   lif_mean1 -> det (overlays p2)
    //   s2pt u16 [40][65][65][128]  @ 169,748,736 (43,264,000)  lif_s2_t -> conv3
    //   wt2b u16 [2][27][4096]      @ 213,012,736 (442,368)
    //   wt3b u16 [4][27][8192]      @ 213,455,104 (1,769,472)   end 215,224,576
    uint8_t* wsb = (uint8_t*)d_ws;
    unsigned short* s1pt = (unsigned short*)(wsb + 256);
    float*   p3     = (float*)(wsb + 256);
    float*   p2     = (float*)(wsb + 85862656u);
    float*   pooled = (float*)(wsb + 85862656u);
    unsigned short* s2pt = (unsigned short*)(wsb + 169748736u);
    unsigned short* wt2b = (unsigned short*)(wsb + 213012736u);
    unsigned short* wt3b = (unsigned short*)(wsb + 213455104u);

    float alpha, beta;
    { uint32_t ab = 0x3F7383C6u; memcpy(&alpha, &ab, 4); }  // e^-0.05f
    { uint32_t bb = 0x3F519857u; memcpy(&beta,  &bb, 4); }  // e^-0.2f

    zpad1t<<<40, 256, 0, stream>>>((uint32_t*)s1pt);
    zpad3b<<<40, 256, 0, stream>>>((uint32_t*)s2pt);
    wtrans2c<<<288, 256, 0, stream>>>(w2, wt2b);
    wtrans3c<<<1152, 256, 0, stream>>>(w3, wt3b);
    conv1_lif<<<dim3(16, 128, 4), 256, 0, stream>>>(x, w1, b1, s1pt, alpha, beta);
    // L2 conv MFMA: grid (64 rows, 2 co-groups, 40 frames) = 5120 blocks
    conv2_mfma<<<dim3(64, 2, 40), 256, 0, stream>>>(s1pt, wt2b, p2);
    lif_s2_t<<<dim3(512, 1, 4), 256, 0, stream>>>(p2, b2, s2pt, alpha, beta);
    // L3 conv MFMA: grid (16 row-pairs, 4 co-groups, 40 frames) = 2560 blocks
    conv3_mfma3<<<dim3(16, 4, 40), 256, 0, stream>>>(s2pt, wt3b, p3);
    lif_mean1<<<dim3(1, 256, 4), 256, 0, stream>>>(p3, b3, pooled, alpha, beta);
    det_conv<<<dim3(16, 4, 4), 256, 0, stream>>>(pooled, wd, bd, out);
}

// Round 4
// 587.709 us; speedup vs baseline: 1.3155x; 1.0130x over previous
//
#include <hip/hip_runtime.h>
#include <stdint.h>
#include <string.h>
#include <cmath>

// SpikingYOLO round 21: barrier-free per-wave MFMA pipelines. Each wave
// stages ITS OWN 16-co weight slice into a private LDS ring (3 slots), so
// no cross-wave sharing exists and every s_barrier is deleted. vmcnt
// inventory identical to R20 (counted, never 0 until tail). s_setprio(1)
// around MFMA clusters (waves now at different phases -> T5 applies).
// Each output computed by the same wave, same MFMA order, same fragments
// as R20 -> layer numerics BIT-IDENTICAL to R20 (absmax 0.0068 expected).

#define BB 4
#define TT 10

typedef short bf16x8 __attribute__((ext_vector_type(8)));
typedef float f32x4  __attribute__((ext_vector_type(4)));

// s1pt: [40][129 rows][130 cols][64 ci] bf16: row stride 8320 elems,
//   plane 1,073,280 elems. s2pt: [40][65][65][128] bf16: row stride 8320,
//   plane 540,800 elems.

// ---------------- zero pads of s1pt (u32 view): plane 536,640 u32,
// row stride 4160 u32; zero row 0 (4160) + col 0 (32 u32) of rows 0..128.
__global__ __launch_bounds__(256) void zpad1t(uint32_t* __restrict__ buf) {
    uint32_t* p = buf + (size_t)blockIdx.x * 536640u;
    for (int i = threadIdx.x; i < 8288; i += 256) {
        if (i < 4160) p[i] = 0u;
        else { int j = i - 4160; p[(j >> 5) * 4160 + (j & 31)] = 0u; }
    }
}

// ---------------- zero pads of s2pt (u32 view): plane 270,400 u32,
// row stride 4160 u32; zero row 0 (4160) + col 0 (64 u32) of rows 0..64.
__global__ __launch_bounds__(256) void zpad3b(uint32_t* __restrict__ buf) {
    uint32_t* p = buf + (size_t)blockIdx.x * 270400u;
    for (int i = threadIdx.x; i < 8320; i += 256) {
        if (i < 4160) p[i] = 0u;
        else { int j = i - 4160; p[(j >> 6) * 4160 + (j & 63)] = 0u; }
    }
}

// ---------------------------------------------------------------- conv1+LIF
// LIF arithmetic bit-identical to R9..R20; stores bf16 spike (0x3F80 / 0).
__global__ __launch_bounds__(256) void conv1_lif(
    const float* __restrict__ x,    // [4,2,128,128,10]
    const float* __restrict__ w1,   // [64,2,3,3]
    const float* __restrict__ b1,   // [64]
    unsigned short* __restrict__ s1pt,  // [40][129][130][64] bf16
    float alpha, float beta)
{
    __shared__ float xs[2][3][10][10];   // [ci][kh][wi][t]
    __shared__ float wsh[18][64];        // [tap][co]
    const int tid = threadIdx.x;
    const int b = blockIdx.z, h = blockIdx.y, w0 = blockIdx.x * 8;

    for (int i = tid; i < 1152; i += 256) {
        int co = i & 63, tap = i >> 6;
        wsh[tap][co] = w1[co * 18 + tap];
    }
    for (int i = tid; i < 600; i += 256) {
        int t = i % 10; int rest = i / 10;
        int wi = rest % 10; rest /= 10;
        int kh = rest % 3; int ci = rest / 3;
        int hh = h - 1 + kh, ww = w0 - 1 + wi;
        float v = 0.f;
        if (hh >= 0 && hh < 128 && ww >= 0 && ww < 128)
            v = x[(((b * 2 + ci) * 128 + hh) * 128 + ww) * 10 + t];
        xs[ci][kh][wi][t] = v;
    }
    __syncthreads();

    const int px  = tid & 7;
    const int cog = (tid >> 3) * 2;
    float acc[2][10];
#pragma unroll
    for (int c = 0; c < 2; ++c)
#pragma unroll
        for (int t = 0; t < 10; ++t) acc[c][t] = 0.f;

#pragma unroll
    for (int tap = 0; tap < 18; ++tap) {
        const int ci = tap / 9, kh = (tap % 9) / 3, kw = tap % 3;
        float2 wv = *(const float2*)&wsh[tap][cog];
#pragma unroll
        for (int t = 0; t < 10; ++t) {
            float xv = xs[ci][kh][px + kw][t];
            acc[0][t] = __fmaf_rn(wv.x, xv, acc[0][t]);
            acc[1][t] = __fmaf_rn(wv.y, xv, acc[1][t]);
        }
    }
#pragma unroll
    for (int c = 0; c < 2; ++c) {
        const float bv = b1[cog + c];
        float syn = 0.f, mem = 0.f;
#pragma unroll
        for (int t = 0; t < 10; ++t) {
            float cur = __fadd_rn(acc[c][t], bv);
            syn = __fadd_rn(__fmul_rn(beta, syn), cur);
            mem = __fadd_rn(__fmul_rn(alpha, mem), syn);
            bool sc = (mem >= 1.0f);
            float sp = sc ? 1.0f : 0.0f;
            mem = __fsub_rn(mem, sp);
            s1pt[(uint32_t)(t * BB + b) * 1073280u
                 + (h + 1) * 8320u + (w0 + px + 1) * 64u + (cog + c)] =
                sc ? (unsigned short)0x3F80 : (unsigned short)0;
        }
    }
}

// --------- w2 -> 3-term bf16 split, staging layout [cobi(2)][tap(9)][term(3)]
// [4096-elem tile]; tile elem = ((wid*2+c)*64 + (g*16+l15))*8 + e holds
// weight(co = cobi*64+wid*16+l15, ci = c*32+g*8+e).
__global__ __launch_bounds__(256) void wtrans2c(
    const float* __restrict__ w2, unsigned short* __restrict__ wtb)
{
    int i = blockIdx.x * 256 + threadIdx.x;
    if (i >= 73728) return;                  // 128*64*9
    int co  = i / 576;
    int rem = i - co * 576;
    int ci  = rem / 9;
    int tap = rem - ci * 9;
    float w = w2[i];                         // [co][ci][kh][kw]
    uint32_t uw  = __float_as_uint(w);
    uint32_t h16 = (uw + 0x7FFFu + ((uw >> 16) & 1u)) >> 16;   // RNE bf16
    float hf = __uint_as_float(h16 << 16);
    float r1 = w - hf;
    uint32_t ur1 = __float_as_uint(r1);
    uint32_t m16 = (ur1 + 0x7FFFu + ((ur1 >> 16) & 1u)) >> 16;
    float mf = __uint_as_float(m16 << 16);
    float r2 = r1 - mf;
    uint32_t ur2 = __float_as_uint(r2);
    uint32_t l16 = (ur2 + 0x7FFFu + ((ur2 >> 16) & 1u)) >> 16;

    int cobi = co >> 6, coL = co & 63;
    int wid = coL >> 4, l15 = coL & 15;
    int c = ci >> 5, r5 = ci & 31;
    int g = r5 >> 3, e = r5 & 7;
    size_t base = (size_t)(cobi * 27 + tap * 3) * 4096
                + (size_t)(((wid * 2 + c) * 64 + (g * 16 + l15)) * 8 + e);
    wtb[base]        = (unsigned short)h16;
    wtb[base + 4096] = (unsigned short)m16;
    wtb[base + 8192] = (unsigned short)l16;
}

// --------- w3 -> 3-term bf16 split, layout [cobi(4)][tap(9)][term(3)]
// [8192-elem tile]; tile elem = ((wq*4+cc)*64 + (g*16+l15))*8 + e holds
// weight(co = cobi*64+wq*16+l15, ci = cc*32+g*8+e).
__global__ __launch_bounds__(256) void wtrans3c(
    const float* __restrict__ w3, unsigned short* __restrict__ wtb)
{
    int i = blockIdx.x * 256 + threadIdx.x;
    if (i >= 294912) return;                 // 256*128*9
    int co  = i / 1152;
    int rem = i - co * 1152;
    int ci  = rem / 9;
    int tap = rem - ci * 9;
    float w = w3[i];                         // [co][ci][kh][kw]
    uint32_t uw  = __float_as_uint(w);
    uint32_t h16 = (uw + 0x7FFFu + ((uw >> 16) & 1u)) >> 16;
    float hf = __uint_as_float(h16 << 16);
    float r1 = w - hf;
    uint32_t ur1 = __float_as_uint(r1);
    uint32_t m16 = (ur1 + 0x7FFFu + ((ur1 >> 16) & 1u)) >> 16;
    float mf = __uint_as_float(m16 << 16);
    float r2 = r1 - mf;
    uint32_t ur2 = __float_as_uint(r2);
    uint32_t l16 = (ur2 + 0x7FFFu + ((ur2 >> 16) & 1u)) >> 16;

    int cobi = co >> 6, coL = co & 63;
    int wq = coL >> 4, l15 = coL & 15;
    int cc = ci >> 5, r5 = ci & 31;
    int g = r5 >> 3, e = r5 & 7;
    size_t base = (size_t)(cobi * 27 + tap * 3) * 8192
                + (size_t)(((wq * 4 + cc) * 64 + (g * 16 + l15)) * 8 + e);
    wtb[base]         = (unsigned short)h16;
    wtb[base + 8192]  = (unsigned short)m16;
    wtb[base + 16384] = (unsigned short)l16;
}

#define VMCNT(n) do { __builtin_amdgcn_sched_barrier(0); \
    asm volatile("s_waitcnt vmcnt(" #n ")" ::: "memory"); \
    __builtin_amdgcn_sched_barrier(0); } while (0)
#define SB() __builtin_amdgcn_sched_barrier(0)
#define PRIO1() __builtin_amdgcn_s_setprio(1)
#define PRIO0() __builtin_amdgcn_s_setprio(0)

// ------------------- L2 conv via MFMA, barrier-free per-wave pipeline.
// Block: 4 waves; each wave owns co-quarter [cobi*64 + wid*16, +16) over
// 64 px (1 output row). Per-wave private LDS ring: 3 slots x 2KB. Per tile:
// 2 global_load_lds (wave's own slice), counted vmcnt, 2 ds_read_b128,
// 8 MFMA. No s_barrier anywhere. Numerics identical to R20.
__global__ __launch_bounds__(256) void conv2_mfma(
    const unsigned short* __restrict__ s1pt,  // [40][129][130][64] bf16
    const unsigned short* __restrict__ wtb,   // [2][27][4096]
    float* __restrict__ p2)                   // [40][4096][128]
{
    __shared__ alignas(16) unsigned short Bs[12288];   // 4 waves x 3 rings x 1024
    const int tid  = threadIdx.x;
    const int lane = tid & 63, wid = tid >> 6;
    const int r = lane & 15, g = lane >> 4;
    const int f = blockIdx.z, cobi = blockIdx.y;
    const int hb = blockIdx.x;                 // output row 0..63

    const unsigned short* fbase = s1pt + (uint32_t)f * 1073280u;
    const unsigned short* wt = wtb + (uint32_t)cobi * (27u * 4096u);
    const int wbase = wid * 3072;

    f32x4 acc[4];
#pragma unroll
    for (int mt = 0; mt < 4; ++mt) acc[mt] = (f32x4){0.f, 0.f, 0.f, 0.f};
    bf16x8 aA[8], aB[8];

#define STAGE2(tt, ring_) do { _Pragma("unroll") \
    for (int c_ = 0; c_ < 2; ++c_) \
        __builtin_amdgcn_global_load_lds( \
            (const __attribute__((address_space(1))) unsigned int*)(const void*)(wt + (uint32_t)(tt) * 4096u + wid * 1024 + c_ * 512 + lane * 8), \
            (__attribute__((address_space(3))) unsigned int*)(void*)(&Bs[wbase + (ring_) * 1024 + c_ * 512 + lane * 8]), \
            16, 0, 0); } while (0)

#define LOADA2(tap_, DST) do { \
    const int kh_ = (tap_) / 3, kw_ = (tap_) % 3; \
    _Pragma("unroll") \
    for (int mt_ = 0; mt_ < 4; ++mt_) { \
        const unsigned short* rp_ = fbase + (uint32_t)(2 * hb + kh_) * 8320u \
            + (uint32_t)(2 * (mt_ * 16 + r) + kw_) * 64u + (uint32_t)g * 8u; \
        _Pragma("unroll") \
        for (int c_ = 0; c_ < 2; ++c_) \
            DST[mt_ * 2 + c_] = *(const bf16x8*)(rp_ + c_ * 32); \
    } } while (0)

#define MTILE2(USE, ring_) do { _Pragma("unroll") \
    for (int c_ = 0; c_ < 2; ++c_) { \
        bf16x8 b_ = *(const bf16x8*)&Bs[wbase + (ring_) * 1024 + c_ * 512 + lane * 8]; \
        acc[0] = __builtin_amdgcn_mfma_f32_16x16x32_bf16(b_, USE[0 + c_], acc[0], 0, 0, 0); \
        acc[1] = __builtin_amdgcn_mfma_f32_16x16x32_bf16(b_, USE[2 + c_], acc[1], 0, 0, 0); \
        acc[2] = __builtin_amdgcn_mfma_f32_16x16x32_bf16(b_, USE[4 + c_], acc[2], 0, 0, 0); \
        acc[3] = __builtin_amdgcn_mfma_f32_16x16x32_bf16(b_, USE[6 + c_], acc[3], 0, 0, 0); \
    } } while (0)

#define TAP2(tap_, USE, NXT) do { \
    STAGE2(3 * (tap_) + 2, 2); VMCNT(4); \
    PRIO1(); MTILE2(USE, 0); PRIO0(); LOADA2((tap_) + 1, NXT); SB(); \
    STAGE2(3 * (tap_) + 3, 0); VMCNT(12); \
    PRIO1(); MTILE2(USE, 1); PRIO0(); SB(); \
    STAGE2(3 * (tap_) + 4, 1); VMCNT(12); \
    PRIO1(); MTILE2(USE, 2); PRIO0(); SB(); \
} while (0)

    LOADA2(0, aA);
    STAGE2(0, 0); STAGE2(1, 1);

    TAP2(0, aA, aB); TAP2(1, aB, aA); TAP2(2, aA, aB); TAP2(3, aB, aA);
    TAP2(4, aA, aB); TAP2(5, aB, aA); TAP2(6, aA, aB); TAP2(7, aB, aA);
    // tap 8 tail (uses aA, no further prefetch)
    STAGE2(26, 2); VMCNT(4);
    PRIO1(); MTILE2(aA, 0); PRIO0(); SB();
    VMCNT(2);
    PRIO1(); MTILE2(aA, 1); PRIO0(); SB();
    VMCNT(0);
    PRIO1(); MTILE2(aA, 2); PRIO0();

#pragma unroll
    for (int mt = 0; mt < 4; ++mt)
        *(f32x4*)&p2[((uint32_t)f * 4096u + hb * 64 + mt * 16 + r) * 128u
                     + cobi * 64 + wid * 16 + g * 4] = acc[mt];
#undef STAGE2
#undef LOADA2
#undef MTILE2
#undef TAP2
}

// ---------------------- LIF layer 2: single MFMA partial -> bf16 spikes.
__global__ __launch_bounds__(256) void lif_s2_t(
    const float* __restrict__ pa, const float* __restrict__ bias,
    unsigned short* __restrict__ s2pt, float alpha, float beta)
{
    const int tid = threadIdx.x;
    const int b   = blockIdx.z;
    const int px  = blockIdx.x * 8 + (tid >> 5);
    const int co0 = (tid & 31) * 4;
    const int h = px >> 6, w = px & 63;
    float4 bv = *(const float4*)&bias[co0];
    const float bva[4] = {bv.x, bv.y, bv.z, bv.w};
    float syn[4] = {0.f,0.f,0.f,0.f}, mem[4] = {0.f,0.f,0.f,0.f};
    unsigned short* sp = s2pt + (uint32_t)(h + 1) * 8320u + (uint32_t)(w + 1) * 128u + co0;
    for (int t = 0; t < TT; ++t) {
        const int f = t * BB + b;
        const uint32_t idx = ((uint32_t)f * 4096u + px) * 128u + co0;
        float4 A = *(const float4*)&pa[idx];
        const float va[4] = {A.x, A.y, A.z, A.w};
        uint32_t pk[2] = {0u, 0u};
#pragma unroll
        for (int j = 0; j < 4; ++j) {
            float c = __fadd_rn(va[j], bva[j]);
            syn[j] = __fadd_rn(__fmul_rn(beta, syn[j]), c);
            mem[j] = __fadd_rn(__fmul_rn(alpha, mem[j]), syn[j]);
            bool sc = (mem[j] >= 1.0f);
            mem[j] = __fsub_rn(mem[j], sc ? 1.0f : 0.0f);
            pk[j >> 1] |= (sc ? 0x3F80u : 0u) << ((j & 1) * 16);
        }
        *(uint2*)(sp + (uint32_t)f * 540800u) = make_uint2(pk[0], pk[1]);
    }
}

// ------------------- L3 conv via MFMA, barrier-free per-wave pipeline.
// Block: 4 waves; wave owns co-quarter over 64 px (2 output rows). Per-wave
// LDS ring: 3 slots x 4KB. Per tile: 4 global_load_lds, counted vmcnt,
// 4 ds_read_b128, 16 MFMA. No s_barrier. Numerics identical to R20.
__global__ __launch_bounds__(256) void conv3_mfma3(
    const unsigned short* __restrict__ s2pt,  // [40][65][65][128] bf16
    const unsigned short* __restrict__ wtb,   // [4][27][8192]
    float* __restrict__ p3)                   // [40][256][32][32]
{
    __shared__ alignas(16) unsigned short Bs[24576];   // 4 waves x 3 rings x 2048
    const int tid  = threadIdx.x;
    const int lane = tid & 63, wid = tid >> 6;
    const int r = lane & 15, g = lane >> 4;
    const int f = blockIdx.z, cobi = blockIdx.y;
    const int h0 = blockIdx.x * 2;

    const unsigned short* fbase = s2pt + (uint32_t)f * 540800u;
    const unsigned short* wt = wtb + (uint32_t)cobi * (27u * 8192u);
    const int wbase = wid * 6144;

    f32x4 acc[4];
#pragma unroll
    for (int mt = 0; mt < 4; ++mt) acc[mt] = (f32x4){0.f, 0.f, 0.f, 0.f};
    bf16x8 aA[16], aB[16];

#define STAGE3(tt, ring_) do { _Pragma("unroll") \
    for (int c_ = 0; c_ < 4; ++c_) \
        __builtin_amdgcn_global_load_lds( \
            (const __attribute__((address_space(1))) unsigned int*)(const void*)(wt + (uint32_t)(tt) * 8192u + wid * 2048 + c_ * 512 + lane * 8), \
            (__attribute__((address_space(3))) unsigned int*)(void*)(&Bs[wbase + (ring_) * 2048 + c_ * 512 + lane * 8]), \
            16, 0, 0); } while (0)

#define LOADA3(tap_, DST) do { \
    const int kh_ = (tap_) / 3, kw_ = (tap_) % 3; \
    _Pragma("unroll") \
    for (int mt_ = 0; mt_ < 4; ++mt_) { \
        const unsigned short* rp_ = fbase + (uint32_t)(2 * h0 + 2 * (mt_ >> 1) + kh_) * 8320u \
            + (uint32_t)(2 * ((mt_ & 1) * 16 + r) + kw_) * 128u + (uint32_t)g * 8u; \
        _Pragma("unroll") \
        for (int c_ = 0; c_ < 4; ++c_) \
            DST[mt_ * 4 + c_] = *(const bf16x8*)(rp_ + c_ * 32); \
    } } while (0)

#define MTILE3(USE, ring_) do { _Pragma("unroll") \
    for (int c_ = 0; c_ < 4; ++c_) { \
        bf16x8 b_ = *(const bf16x8*)&Bs[wbase + (ring_) * 2048 + c_ * 512 + lane * 8]; \
        acc[0] = __builtin_amdgcn_mfma_f32_16x16x32_bf16(USE[0 + c_],  b_, acc[0], 0, 0, 0); \
        acc[1] = __builtin_amdgcn_mfma_f32_16x16x32_bf16(USE[4 + c_],  b_, acc[1], 0, 0, 0); \
        acc[2] = __builtin_amdgcn_mfma_f32_16x16x32_bf16(USE[8 + c_],  b_, acc[2], 0, 0, 0); \
        acc[3] = __builtin_amdgcn_mfma_f32_16x16x32_bf16(USE[12 + c_], b_, acc[3], 0, 0, 0); \
    } } while (0)

#define TAP3(tap_, USE, NXT) do { \
    STAGE3(3 * (tap_) + 2, 2); VMCNT(8); \
    PRIO1(); MTILE3(USE, 0); PRIO0(); LOADA3((tap_) + 1, NXT); SB(); \
    STAGE3(3 * (tap_) + 3, 0); VMCNT(24); \
    PRIO1(); MTILE3(USE, 1); PRIO0(); SB(); \
    STAGE3(3 * (tap_) + 4, 1); VMCNT(24); \
    PRIO1(); MTILE3(USE, 2); PRIO0(); SB(); \
} while (0)

    LOADA3(0, aA);
    STAGE3(0, 0); STAGE3(1, 1);

    TAP3(0, aA, aB); TAP3(1, aB, aA); TAP3(2, aA, aB); TAP3(3, aB, aA);
    TAP3(4, aA, aB); TAP3(5, aB, aA); TAP3(6, aA, aB); TAP3(7, aB, aA);
    // tap 8 tail (uses aA, no further prefetch)
    STAGE3(26, 2); VMCNT(8);
    PRIO1(); MTILE3(aA, 0); PRIO0(); SB();
    VMCNT(4);
    PRIO1(); MTILE3(aA, 1); PRIO0(); SB();
    VMCNT(0);
    PRIO1(); MTILE3(aA, 2); PRIO0();

    const int cob = cobi * 64;
#pragma unroll
    for (int mt = 0; mt < 4; ++mt) {
        const int hh = h0 + (mt >> 1);
        const int wc = (mt & 1) * 16 + g * 4;
        *(f32x4*)&p3[((uint32_t)(f * 256 + cob + wid * 16 + r) * 32u + hh) * 32u + wc] = acc[mt];
    }
#undef STAGE3
#undef LOADA3
#undef MTILE3
#undef TAP3
}

// ---------------------- LIF + time-mean from the single conv3 buffer
__global__ __launch_bounds__(256) void lif_mean1(
    const float* __restrict__ p3, const float* __restrict__ bias,
    float* __restrict__ pooled, float alpha, float beta)
{
    const int px = (blockIdx.x * 256 + threadIdx.x) * 4;
    const int co = blockIdx.y;
    const int b  = blockIdx.z;
    const float bv = bias[co];
    float syn[4] = {0.f,0.f,0.f,0.f}, mem[4] = {0.f,0.f,0.f,0.f};
    float sum[4] = {0.f,0.f,0.f,0.f};
    for (int t = 0; t < TT; ++t) {
        const int idx = ((t * BB + b) * 256 + co) * 1024 + px;
        float4 a = *(const float4*)&p3[idx];
        const float va[4] = {a.x, a.y, a.z, a.w};
#pragma unroll
        for (int j = 0; j < 4; ++j) {
            float cu = __fadd_rn(va[j], bv);
            syn[j] = __fadd_rn(__fmul_rn(beta, syn[j]), cu);
            mem[j] = __fadd_rn(__fmul_rn(alpha, mem[j]), syn[j]);
            bool sc = (mem[j] >= 1.0f);
            float sp = sc ? 1.0f : 0.0f;
            mem[j] = __fsub_rn(mem[j], sp);
            sum[j] = __fadd_rn(sum[j], sp);
        }
    }
    *(float4*)&pooled[(b * 256 + co) * 1024 + px] =
        make_float4(sum[0] / 10.0f, sum[1] / 10.0f, sum[2] / 10.0f, sum[3] / 10.0f);
}

// ------------------------------------------------------------------ det 1x1
__global__ __launch_bounds__(256) void det_conv(
    const float* __restrict__ pooled, // [4,256,1024]
    const float* __restrict__ wd,     // [255,256]
    const float* __restrict__ bd,     // [255]
    float* __restrict__ out)          // [4,255,1024]
{
    __shared__ float wtl[16][64];
    __shared__ float ps[16][64];
    const int tid = threadIdx.x;
    const int b = blockIdx.z;
    const int o_base = blockIdx.y * 64;
    const int px_base = blockIdx.x * 64;
    const int o_off = (tid >> 4) * 4;
    const int px_off = (tid & 15) * 4;
    float acc[4][4];
#pragma unroll
    for (int c = 0; c < 4; ++c) {
        int o = o_base + o_off + c;
        float bv = (o < 255) ? bd[o] : 0.f;
#pragma unroll
        for (int j = 0; j < 4; ++j) acc[c][j] = bv;
    }
    for (int cc = 0; cc < 16; ++cc) {
        for (int k = tid; k < 1024; k += 256) {
            int o = k & 63, ci = k >> 6;
            wtl[ci][o] = (o_base + o < 255) ? wd[(o_base + o) * 256 + cc * 16 + ci] : 0.f;
            ps[ci][o] = pooled[(b * 256 + cc * 16 + ci) * 1024 + px_base + o];
        }
        __syncthreads();
#pragma unroll
        for (int ci = 0; ci < 16; ++ci) {
            float4 wv = *(const float4*)&wtl[ci][o_off];
            float4 sv = *(const float4*)&ps[ci][px_off];
            acc[0][0] += wv.x * sv.x; acc[0][1] += wv.x * sv.y;
            acc[0][2] += wv.x * sv.z; acc[0][3] += wv.x * sv.w;
            acc[1][0] += wv.y * sv.x; acc[1][1] += wv.y * sv.y;
            acc[1][2] += wv.y * sv.z; acc[1][3] += wv.y * sv.w;
            acc[2][0] += wv.z * sv.x; acc[2][1] += wv.z * sv.y;
            acc[2][2] += wv.z * sv.z; acc[2][3] += wv.z * sv.w;
            acc[3][0] += wv.w * sv.x; acc[3][1] += wv.w * sv.y;
            acc[3][2] += wv.w * sv.z; acc[3][3] += wv.w * sv.w;
        }
        __syncthreads();
    }
#pragma unroll
    for (int c = 0; c < 4; ++c) {
        int o = o_base + o_off + c;
        if (o < 255)
            *(float4*)&out[(b * 255 + o) * 1024 + px_base + px_off] =
                make_float4(acc[c][0], acc[c][1], acc[c][2], acc[c][3]);
    }
}

extern "C" void kernel_launch(void* const* d_in, const int* in_sizes, int n_in,
                              void* d_out, int out_size, void* d_ws, size_t ws_size,
                              hipStream_t stream) {
    const float* x  = (const float*)d_in[0];
    const float* w1 = (const float*)d_in[1];
    const float* b1 = (const float*)d_in[2];
    const float* w2 = (const float*)d_in[3];
    const float* b2 = (const float*)d_in[4];
    const float* w3 = (const float*)d_in[5];
    const float* b3 = (const float*)d_in[6];
    const float* wd = (const float*)d_in[7];
    const float* bd = (const float*)d_in[8];
    float* out = (float*)d_out;

    // ws layout with aliasing (lifetimes; ~215.2 MB):
    //   s1pt u16 [40][129][130][64] @ 256         (85,862,400)  conv1 -> conv2
    //   p3   f32 [40*256*1024]      @ 256         (41,943,040)  conv3 -> lif_mean1 (overlays s1pt)
    //   p2   f32 [40][4096][128]    @ 85,862,656  (83,886,080)  conv2 -> lif_s2_t
    //   pooled f32                  @ 85,862,656  (4,194,304)   lif_mean1 -> det (overlays p2)
    //   s2pt u16 [40][65][65][128]  @ 169,748,736 (43,264,000)  lif_s2_t -> conv3
    //   wt2b u16 [2][27][4096]      @ 213,012,736 (442,368)
    //   wt3b u16 [4][27][8192]      @ 213,455,104 (1,769,472)   end 215,224,576
    uint8_t* wsb = (uint8_t*)d_ws;
    unsigned short* s1pt = (unsigned short*)(wsb + 256);
    float*   p3     = (float*)(wsb + 256);
    float*   p2     = (float*)(wsb + 85862656u);
    float*   pooled = (float*)(wsb + 85862656u);
    unsigned short* s2pt = (unsigned short*)(wsb + 169748736u);
    unsigned short* wt2b = (unsigned short*)(wsb + 213012736u);
    unsigned short* wt3b = (unsigned short*)(wsb + 213455104u);

    float alpha, beta;
    { uint32_t ab = 0x3F7383C6u; memcpy(&alpha, &ab, 4); }  // e^-0.05f
    { uint32_t bb = 0x3F519857u; memcpy(&beta,  &bb, 4); }  // e^-0.2f

    zpad1t<<<40, 256, 0, stream>>>((uint32_t*)s1pt);
    zpad3b<<<40, 256, 0, stream>>>((uint32_t*)s2pt);
    wtrans2c<<<288, 256, 0, stream>>>(w2, wt2b);
    wtrans3c<<<1152, 256, 0, stream>>>(w3, wt3b);
    conv1_lif<<<dim3(16, 128, 4), 256, 0, stream>>>(x, w1, b1, s1pt, alpha, beta);
    // L2 conv MFMA: grid (64 rows, 2 co-groups, 40 frames) = 5120 blocks
    conv2_mfma<<<dim3(64, 2, 40), 256, 0, stream>>>(s1pt, wt2b, p2);
    lif_s2_t<<<dim3(512, 1, 4), 256, 0, stream>>>(p2, b2, s2pt, alpha, beta);
    // L3 conv MFMA: grid (16 row-pairs, 4 co-groups, 40 frames) = 2560 blocks
    conv3_mfma3<<<dim3(16, 4, 40), 256, 0, stream>>>(s2pt, wt3b, p3);
    lif_mean1<<<dim3(1, 256, 4), 256, 0, stream>>>(p3, b3, pooled, alpha, beta);
    det_conv<<<dim3(16, 4, 4), 256, 0, stream>>>(pooled, wd, bd, out);
}

// Round 5
// 583.218 us; speedup vs baseline: 1.3257x; 1.0077x over previous
//
#include <hip/hip_runtime.h>
#include <stdint.h>
#include <string.h>
#include <cmath>

// SpikingYOLO round 23: register-resident MFMA pipelines, ONE vmcnt wait per
// phase. Phase = {issue next-phase 6 B-frags + 8 A-frags into alternate reg
// buffers -> vmcnt(14) -> 24-MFMA cluster}. Zero LDS in both convs (no
// staging, no ds_read, no barriers). Prefetch distance = one full phase
// (covers L2/most HBM latency) vs R21/R22's ~100cy. conv2 accumulation order
// BIT-IDENTICAL to R21/R22. conv3 split into half-tap phases (term/chunk
// order interchange; same product set, rounding-level change only).

#define BB 4
#define TT 10

typedef short bf16x8 __attribute__((ext_vector_type(8)));
typedef float f32x4  __attribute__((ext_vector_type(4)));

#define MFMA16(a, b, c) __builtin_amdgcn_mfma_f32_16x16x32_bf16((a), (b), (c), 0, 0, 0)

// s1pt: [40][129 rows][130 cols][64 ci] bf16: row stride 8320 elems,
//   plane 1,073,280 elems. s2pt: [40][65][65][128] bf16: row stride 8320,
//   plane 540,800 elems.

// ---------------- zero pads of s1pt (u32 view): plane 536,640 u32,
// row stride 4160 u32; zero row 0 (4160) + col 0 (32 u32) of rows 0..128.
__global__ __launch_bounds__(256) void zpad1t(uint32_t* __restrict__ buf) {
    uint32_t* p = buf + (size_t)blockIdx.x * 536640u;
    for (int i = threadIdx.x; i < 8288; i += 256) {
        if (i < 4160) p[i] = 0u;
        else { int j = i - 4160; p[(j >> 5) * 4160 + (j & 31)] = 0u; }
    }
}

// ---------------- zero pads of s2pt (u32 view): plane 270,400 u32,
// row stride 4160 u32; zero row 0 (4160) + col 0 (64 u32) of rows 0..64.
__global__ __launch_bounds__(256) void zpad3b(uint32_t* __restrict__ buf) {
    uint32_t* p = buf + (size_t)blockIdx.x * 270400u;
    for (int i = threadIdx.x; i < 8320; i += 256) {
        if (i < 4160) p[i] = 0u;
        else { int j = i - 4160; p[(j >> 6) * 4160 + (j & 63)] = 0u; }
    }
}

// ---------------------------------------------------------------- conv1+LIF
// LIF arithmetic bit-identical to R9..R22; stores bf16 spike (0x3F80 / 0).
__global__ __launch_bounds__(256) void conv1_lif(
    const float* __restrict__ x,    // [4,2,128,128,10]
    const float* __restrict__ w1,   // [64,2,3,3]
    const float* __restrict__ b1,   // [64]
    unsigned short* __restrict__ s1pt,  // [40][129][130][64] bf16
    float alpha, float beta)
{
    __shared__ float xs[2][3][10][10];   // [ci][kh][wi][t]
    __shared__ float wsh[18][64];        // [tap][co]
    const int tid = threadIdx.x;
    const int b = blockIdx.z, h = blockIdx.y, w0 = blockIdx.x * 8;

    for (int i = tid; i < 1152; i += 256) {
        int co = i & 63, tap = i >> 6;
        wsh[tap][co] = w1[co * 18 + tap];
    }
    for (int i = tid; i < 600; i += 256) {
        int t = i % 10; int rest = i / 10;
        int wi = rest % 10; rest /= 10;
        int kh = rest % 3; int ci = rest / 3;
        int hh = h - 1 + kh, ww = w0 - 1 + wi;
        float v = 0.f;
        if (hh >= 0 && hh < 128 && ww >= 0 && ww < 128)
            v = x[(((b * 2 + ci) * 128 + hh) * 128 + ww) * 10 + t];
        xs[ci][kh][wi][t] = v;
    }
    __syncthreads();

    const int px  = tid & 7;
    const int cog = (tid >> 3) * 2;
    float acc[2][10];
#pragma unroll
    for (int c = 0; c < 2; ++c)
#pragma unroll
        for (int t = 0; t < 10; ++t) acc[c][t] = 0.f;

#pragma unroll
    for (int tap = 0; tap < 18; ++tap) {
        const int ci = tap / 9, kh = (tap % 9) / 3, kw = tap % 3;
        float2 wv = *(const float2*)&wsh[tap][cog];
#pragma unroll
        for (int t = 0; t < 10; ++t) {
            float xv = xs[ci][kh][px + kw][t];
            acc[0][t] = __fmaf_rn(wv.x, xv, acc[0][t]);
            acc[1][t] = __fmaf_rn(wv.y, xv, acc[1][t]);
        }
    }
#pragma unroll
    for (int c = 0; c < 2; ++c) {
        const float bv = b1[cog + c];
        float syn = 0.f, mem = 0.f;
#pragma unroll
        for (int t = 0; t < 10; ++t) {
            float cur = __fadd_rn(acc[c][t], bv);
            syn = __fadd_rn(__fmul_rn(beta, syn), cur);
            mem = __fadd_rn(__fmul_rn(alpha, mem), syn);
            bool sc = (mem >= 1.0f);
            float sp = sc ? 1.0f : 0.0f;
            mem = __fsub_rn(mem, sp);
            s1pt[(uint32_t)(t * BB + b) * 1073280u
                 + (h + 1) * 8320u + (w0 + px + 1) * 64u + (cog + c)] =
                sc ? (unsigned short)0x3F80 : (unsigned short)0;
        }
    }
}

// --------- w2 -> 3-term bf16 split, layout [cobi(2)][tap(9)][term(3)]
// [4096-elem tile]; tile elem = ((wid*2+c)*64 + (g*16+l15))*8 + e holds
// weight(co = cobi*64+wid*16+l15, ci = c*32+g*8+e).
__global__ __launch_bounds__(256) void wtrans2c(
    const float* __restrict__ w2, unsigned short* __restrict__ wtb)
{
    int i = blockIdx.x * 256 + threadIdx.x;
    if (i >= 73728) return;                  // 128*64*9
    int co  = i / 576;
    int rem = i - co * 576;
    int ci  = rem / 9;
    int tap = rem - ci * 9;
    float w = w2[i];                         // [co][ci][kh][kw]
    uint32_t uw  = __float_as_uint(w);
    uint32_t h16 = (uw + 0x7FFFu + ((uw >> 16) & 1u)) >> 16;   // RNE bf16
    float hf = __uint_as_float(h16 << 16);
    float r1 = w - hf;
    uint32_t ur1 = __float_as_uint(r1);
    uint32_t m16 = (ur1 + 0x7FFFu + ((ur1 >> 16) & 1u)) >> 16;
    float mf = __uint_as_float(m16 << 16);
    float r2 = r1 - mf;
    uint32_t ur2 = __float_as_uint(r2);
    uint32_t l16 = (ur2 + 0x7FFFu + ((ur2 >> 16) & 1u)) >> 16;

    int cobi = co >> 6, coL = co & 63;
    int wid = coL >> 4, l15 = coL & 15;
    int c = ci >> 5, r5 = ci & 31;
    int g = r5 >> 3, e = r5 & 7;
    size_t base = (size_t)(cobi * 27 + tap * 3) * 4096
                + (size_t)(((wid * 2 + c) * 64 + (g * 16 + l15)) * 8 + e);
    wtb[base]        = (unsigned short)h16;
    wtb[base + 4096] = (unsigned short)m16;
    wtb[base + 8192] = (unsigned short)l16;
}

// --------- w3 -> 3-term bf16 split, layout [cobi(4)][tap(9)][term(3)]
// [8192-elem tile]; tile elem = ((wq*4+cc)*64 + (g*16+l15))*8 + e holds
// weight(co = cobi*64+wq*16+l15, ci = cc*32+g*8+e).
__global__ __launch_bounds__(256) void wtrans3c(
    const float* __restrict__ w3, unsigned short* __restrict__ wtb)
{
    int i = blockIdx.x * 256 + threadIdx.x;
    if (i >= 294912) return;                 // 256*128*9
    int co  = i / 1152;
    int rem = i - co * 1152;
    int ci  = rem / 9;
    int tap = rem - ci * 9;
    float w = w3[i];                         // [co][ci][kh][kw]
    uint32_t uw  = __float_as_uint(w);
    uint32_t h16 = (uw + 0x7FFFu + ((uw >> 16) & 1u)) >> 16;
    float hf = __uint_as_float(h16 << 16);
    float r1 = w - hf;
    uint32_t ur1 = __float_as_uint(r1);
    uint32_t m16 = (ur1 + 0x7FFFu + ((ur1 >> 16) & 1u)) >> 16;
    float mf = __uint_as_float(m16 << 16);
    float r2 = r1 - mf;
    uint32_t ur2 = __float_as_uint(r2);
    uint32_t l16 = (ur2 + 0x7FFFu + ((ur2 >> 16) & 1u)) >> 16;

    int cobi = co >> 6, coL = co & 63;
    int wq = coL >> 4, l15 = coL & 15;
    int cc = ci >> 5, r5 = ci & 31;
    int g = r5 >> 3, e = r5 & 7;
    size_t base = (size_t)(cobi * 27 + tap * 3) * 8192
                + (size_t)(((wq * 4 + cc) * 64 + (g * 16 + l15)) * 8 + e);
    wtb[base]         = (unsigned short)h16;
    wtb[base + 8192]  = (unsigned short)m16;
    wtb[base + 16384] = (unsigned short)l16;
}

#define VMCNT(n) do { __builtin_amdgcn_sched_barrier(0); \
    asm volatile("s_waitcnt vmcnt(" #n ")" ::: "memory"); \
    __builtin_amdgcn_sched_barrier(0); } while (0)
#define SB() __builtin_amdgcn_sched_barrier(0)
#define PRIO1() __builtin_amdgcn_s_setprio(1)
#define PRIO0() __builtin_amdgcn_s_setprio(0)

// ------------------- L2 conv via MFMA, register-resident pipeline.
// Block: 4 waves; wave owns co-quarter [cobi*64+wid*16,+16) x 64 px (1 row).
// Phase = tap: issue next tap's 6 B-frags + 8 A-frags (dbuf regs),
// vmcnt(14), 24-MFMA cluster. Accumulation order identical to R21/R22.
__global__ __launch_bounds__(256) void conv2_mfma(
    const unsigned short* __restrict__ s1pt,  // [40][129][130][64] bf16
    const unsigned short* __restrict__ wtb,   // [2][27][4096]
    float* __restrict__ p2)                   // [40][4096][128]
{
    const int tid  = threadIdx.x;
    const int lane = tid & 63, wid = tid >> 6;
    const int r = lane & 15, g = lane >> 4;
    const int f = blockIdx.z, cobi = blockIdx.y;
    const int hb = blockIdx.x;                 // output row 0..63

    const unsigned short* sA = s1pt + (uint32_t)f * 1073280u
        + (uint32_t)(2 * hb) * 8320u + (uint32_t)(2 * r) * 64u + (uint32_t)g * 8u;
    const unsigned short* wB = wtb + (uint32_t)cobi * (27u * 4096u)
        + (uint32_t)wid * 1024u + (uint32_t)lane * 8u;

    f32x4 acc[4];
#pragma unroll
    for (int mt = 0; mt < 4; ++mt) acc[mt] = (f32x4){0.f, 0.f, 0.f, 0.f};
    bf16x8 aA[8], aB[8], bA[6], bB[6];

#define LOADB2(tap_, DST) do { _Pragma("unroll") \
    for (int t_ = 0; t_ < 3; ++t_) { _Pragma("unroll") \
        for (int c_ = 0; c_ < 2; ++c_) \
            DST[t_ * 2 + c_] = *(const bf16x8*)(wB + (uint32_t)((tap_) * 3 + t_) * 4096u + c_ * 512u); \
    } } while (0)

#define LOADA2(tap_, DST) do { \
    const int kh_ = (tap_) / 3, kw_ = (tap_) % 3; \
    _Pragma("unroll") \
    for (int mt_ = 0; mt_ < 4; ++mt_) { _Pragma("unroll") \
        for (int c_ = 0; c_ < 2; ++c_) \
            DST[mt_ * 2 + c_] = *(const bf16x8*)(sA + (uint32_t)kh_ * 8320u \
                + (uint32_t)(mt_ * 32 + kw_) * 64u + c_ * 32u); \
    } } while (0)

#define CL2(AU, BU) do { _Pragma("unroll") \
    for (int t_ = 0; t_ < 3; ++t_) { _Pragma("unroll") \
        for (int c_ = 0; c_ < 2; ++c_) { \
            bf16x8 b_ = BU[t_ * 2 + c_]; \
            acc[0] = MFMA16(b_, AU[0 + c_], acc[0]); \
            acc[1] = MFMA16(b_, AU[2 + c_], acc[1]); \
            acc[2] = MFMA16(b_, AU[4 + c_], acc[2]); \
            acc[3] = MFMA16(b_, AU[6 + c_], acc[3]); \
        } } } while (0)

#define PH2(tap_, AU, BU, AN, BN) do { \
    SB(); LOADB2((tap_) + 1, BN); LOADA2((tap_) + 1, AN); SB(); \
    VMCNT(14); \
    PRIO1(); CL2(AU, BU); PRIO0(); SB(); \
} while (0)

    LOADB2(0, bA); LOADA2(0, aA);
    PH2(0, aA, bA, aB, bB); PH2(1, aB, bB, aA, bA);
    PH2(2, aA, bA, aB, bB); PH2(3, aB, bB, aA, bA);
    PH2(4, aA, bA, aB, bB); PH2(5, aB, bB, aA, bA);
    PH2(6, aA, bA, aB, bB); PH2(7, aB, bB, aA, bA);
    // tap 8 tail
    SB(); VMCNT(0);
    PRIO1(); CL2(aA, bA); PRIO0();

#pragma unroll
    for (int mt = 0; mt < 4; ++mt)
        *(f32x4*)&p2[((uint32_t)f * 4096u + hb * 64 + mt * 16 + r) * 128u
                     + cobi * 64 + wid * 16 + g * 4] = acc[mt];
#undef LOADB2
#undef LOADA2
#undef CL2
#undef PH2
}

// ---------------------- LIF layer 2: single MFMA partial -> bf16 spikes.
__global__ __launch_bounds__(256) void lif_s2_t(
    const float* __restrict__ pa, const float* __restrict__ bias,
    unsigned short* __restrict__ s2pt, float alpha, float beta)
{
    const int tid = threadIdx.x;
    const int b   = blockIdx.z;
    const int px  = blockIdx.x * 8 + (tid >> 5);
    const int co0 = (tid & 31) * 4;
    const int h = px >> 6, w = px & 63;
    float4 bv = *(const float4*)&bias[co0];
    const float bva[4] = {bv.x, bv.y, bv.z, bv.w};
    float syn[4] = {0.f,0.f,0.f,0.f}, mem[4] = {0.f,0.f,0.f,0.f};
    unsigned short* sp = s2pt + (uint32_t)(h + 1) * 8320u + (uint32_t)(w + 1) * 128u + co0;
    for (int t = 0; t < TT; ++t) {
        const int f = t * BB + b;
        const uint32_t idx = ((uint32_t)f * 4096u + px) * 128u + co0;
        float4 A = *(const float4*)&pa[idx];
        const float va[4] = {A.x, A.y, A.z, A.w};
        uint32_t pk[2] = {0u, 0u};
#pragma unroll
        for (int j = 0; j < 4; ++j) {
            float c = __fadd_rn(va[j], bva[j]);
            syn[j] = __fadd_rn(__fmul_rn(beta, syn[j]), c);
            mem[j] = __fadd_rn(__fmul_rn(alpha, mem[j]), syn[j]);
            bool sc = (mem[j] >= 1.0f);
            mem[j] = __fsub_rn(mem[j], sc ? 1.0f : 0.0f);
            pk[j >> 1] |= (sc ? 0x3F80u : 0u) << ((j & 1) * 16);
        }
        *(uint2*)(sp + (uint32_t)f * 540800u) = make_uint2(pk[0], pk[1]);
    }
}

// ------------------- L3 conv via MFMA, register-resident pipeline.
// Block: 4 waves; wave owns co-quarter x 64 px (2 output rows).
// Phase = half-tap (c_-chunks {0,1} or {2,3}): issue next half's 6 B + 8 A
// frags, vmcnt(14), 24-MFMA cluster. 18 phases. Product set identical to
// R21/R22; accumulation order interchanges term<->chunk (rounding-level).
__global__ __launch_bounds__(256) void conv3_mfma3(
    const unsigned short* __restrict__ s2pt,  // [40][65][65][128] bf16
    const unsigned short* __restrict__ wtb,   // [4][27][8192]
    float* __restrict__ p3)                   // [40][256][32][32]
{
    const int tid  = threadIdx.x;
    const int lane = tid & 63, wid = tid >> 6;
    const int r = lane & 15, g = lane >> 4;
    const int f = blockIdx.z, cobi = blockIdx.y;
    const int h0 = blockIdx.x * 2;

    const unsigned short* sA = s2pt + (uint32_t)f * 540800u
        + (uint32_t)(2 * h0) * 8320u + (uint32_t)(2 * r) * 128u + (uint32_t)g * 8u;
    const unsigned short* wB = wtb + (uint32_t)cobi * (27u * 8192u)
        + (uint32_t)wid * 2048u + (uint32_t)lane * 8u;

    f32x4 acc[4];
#pragma unroll
    for (int mt = 0; mt < 4; ++mt) acc[mt] = (f32x4){0.f, 0.f, 0.f, 0.f};
    bf16x8 aA[8], aB[8], bA[6], bB[6];

#define LOADB3(tap_, half_, DST) do { _Pragma("unroll") \
    for (int t_ = 0; t_ < 3; ++t_) { _Pragma("unroll") \
        for (int j_ = 0; j_ < 2; ++j_) \
            DST[t_ * 2 + j_] = *(const bf16x8*)(wB + (uint32_t)((tap_) * 3 + t_) * 8192u \
                + (uint32_t)((half_) * 2 + j_) * 512u); \
    } } while (0)

#define LOADA3(tap_, half_, DST) do { \
    const int kh_ = (tap_) / 3, kw_ = (tap_) % 3; \
    _Pragma("unroll") \
    for (int mt_ = 0; mt_ < 4; ++mt_) { _Pragma("unroll") \
        for (int j_ = 0; j_ < 2; ++j_) \
            DST[mt_ * 2 + j_] = *(const bf16x8*)(sA + (uint32_t)(2 * (mt_ >> 1) + kh_) * 8320u \
                + (uint32_t)((mt_ & 1) * 32 + kw_) * 128u + (uint32_t)((half_) * 2 + j_) * 32u); \
    } } while (0)

#define CL3(AU, BU) do { _Pragma("unroll") \
    for (int t_ = 0; t_ < 3; ++t_) { _Pragma("unroll") \
        for (int j_ = 0; j_ < 2; ++j_) { \
            bf16x8 b_ = BU[t_ * 2 + j_]; \
            acc[0] = MFMA16(AU[0 + j_], b_, acc[0]); \
            acc[1] = MFMA16(AU[2 + j_], b_, acc[1]); \
            acc[2] = MFMA16(AU[4 + j_], b_, acc[2]); \
            acc[3] = MFMA16(AU[6 + j_], b_, acc[3]); \
        } } } while (0)

#define PH3(ntap_, nhalf_, AU, BU, AN, BN) do { \
    SB(); LOADB3(ntap_, nhalf_, BN); LOADA3(ntap_, nhalf_, AN); SB(); \
    VMCNT(14); \
    PRIO1(); CL3(AU, BU); PRIO0(); SB(); \
} while (0)

    LOADB3(0, 0, bA); LOADA3(0, 0, aA);
    PH3(0, 1, aA, bA, aB, bB); PH3(1, 0, aB, bB, aA, bA);
    PH3(1, 1, aA, bA, aB, bB); PH3(2, 0, aB, bB, aA, bA);
    PH3(2, 1, aA, bA, aB, bB); PH3(3, 0, aB, bB, aA, bA);
    PH3(3, 1, aA, bA, aB, bB); PH3(4, 0, aB, bB, aA, bA);
    PH3(4, 1, aA, bA, aB, bB); PH3(5, 0, aB, bB, aA, bA);
    PH3(5, 1, aA, bA, aB, bB); PH3(6, 0, aB, bB, aA, bA);
    PH3(6, 1, aA, bA, aB, bB); PH3(7, 0, aB, bB, aA, bA);
    PH3(7, 1, aA, bA, aB, bB); PH3(8, 0, aB, bB, aA, bA);
    PH3(8, 1, aA, bA, aB, bB);
    // phase 17 tail (tap 8, half 1) uses aB/bB
    SB(); VMCNT(0);
    PRIO1(); CL3(aB, bB); PRIO0();

    const int cob = cobi * 64;
#pragma unroll
    for (int mt = 0; mt < 4; ++mt) {
        const int hh = h0 + (mt >> 1);
        const int wc = (mt & 1) * 16 + g * 4;
        *(f32x4*)&p3[((uint32_t)(f * 256 + cob + wid * 16 + r) * 32u + hh) * 32u + wc] = acc[mt];
    }
#undef LOADB3
#undef LOADA3
#undef CL3
#undef PH3
}

// ---------------------- LIF + time-mean from the single conv3 buffer
__global__ __launch_bounds__(256) void lif_mean1(
    const float* __restrict__ p3, const float* __restrict__ bias,
    float* __restrict__ pooled, float alpha, float beta)
{
    const int px = (blockIdx.x * 256 + threadIdx.x) * 4;
    const int co = blockIdx.y;
    const int b  = blockIdx.z;
    const float bv = bias[co];
    float syn[4] = {0.f,0.f,0.f,0.f}, mem[4] = {0.f,0.f,0.f,0.f};
    float sum[4] = {0.f,0.f,0.f,0.f};
    for (int t = 0; t < TT; ++t) {
        const int idx = ((t * BB + b) * 256 + co) * 1024 + px;
        float4 a = *(const float4*)&p3[idx];
        const float va[4] = {a.x, a.y, a.z, a.w};
#pragma unroll
        for (int j = 0; j < 4; ++j) {
            float cu = __fadd_rn(va[j], bv);
            syn[j] = __fadd_rn(__fmul_rn(beta, syn[j]), cu);
            mem[j] = __fadd_rn(__fmul_rn(alpha, mem[j]), syn[j]);
            bool sc = (mem[j] >= 1.0f);
            float sp = sc ? 1.0f : 0.0f;
            mem[j] = __fsub_rn(mem[j], sp);
            sum[j] = __fadd_rn(sum[j], sp);
        }
    }
    *(float4*)&pooled[(b * 256 + co) * 1024 + px] =
        make_float4(sum[0] / 10.0f, sum[1] / 10.0f, sum[2] / 10.0f, sum[3] / 10.0f);
}

// ------------------------------------------------------------------ det 1x1
__global__ __launch_bounds__(256) void det_conv(
    const float* __restrict__ pooled, // [4,256,1024]
    const float* __restrict__ wd,     // [255,256]
    const float* __restrict__ bd,     // [255]
    float* __restrict__ out)          // [4,255,1024]
{
    __shared__ float wtl[16][64];
    __shared__ float ps[16][64];
    const int tid = threadIdx.x;
    const int b = blockIdx.z;
    const int o_base = blockIdx.y * 64;
    const int px_base = blockIdx.x * 64;
    const int o_off = (tid >> 4) * 4;
    const int px_off = (tid & 15) * 4;
    float acc[4][4];
#pragma unroll
    for (int c = 0; c < 4; ++c) {
        int o = o_base + o_off + c;
        float bv = (o < 255) ? bd[o] : 0.f;
#pragma unroll
        for (int j = 0; j < 4; ++j) acc[c][j] = bv;
    }
    for (int cc = 0; cc < 16; ++cc) {
        for (int k = tid; k < 1024; k += 256) {
            int o = k & 63, ci = k >> 6;
            wtl[ci][o] = (o_base + o < 255) ? wd[(o_base + o) * 256 + cc * 16 + ci] : 0.f;
            ps[ci][o] = pooled[(b * 256 + cc * 16 + ci) * 1024 + px_base + o];
        }
        __syncthreads();
#pragma unroll
        for (int ci = 0; ci < 16; ++ci) {
            float4 wv = *(const float4*)&wtl[ci][o_off];
            float4 sv = *(const float4*)&ps[ci][px_off];
            acc[0][0] += wv.x * sv.x; acc[0][1] += wv.x * sv.y;
            acc[0][2] += wv.x * sv.z; acc[0][3] += wv.x * sv.w;
            acc[1][0] += wv.y * sv.x; acc[1][1] += wv.y * sv.y;
            acc[1][2] += wv.y * sv.z; acc[1][3] += wv.y * sv.w;
            acc[2][0] += wv.z * sv.x; acc[2][1] += wv.z * sv.y;
            acc[2][2] += wv.z * sv.z; acc[2][3] += wv.z * sv.w;
            acc[3][0] += wv.w * sv.x; acc[3][1] += wv.w * sv.y;
            acc[3][2] += wv.w * sv.z; acc[3][3] += wv.w * sv.w;
        }
        __syncthreads();
    }
#pragma unroll
    for (int c = 0; c < 4; ++c) {
        int o = o_base + o_off + c;
        if (o < 255)
            *(float4*)&out[(b * 255 + o) * 1024 + px_base + px_off] =
                make_float4(acc[c][0], acc[c][1], acc[c][2], acc[c][3]);
    }
}

extern "C" void kernel_launch(void* const* d_in, const int* in_sizes, int n_in,
                              void* d_out, int out_size, void* d_ws, size_t ws_size,
                              hipStream_t stream) {
    const float* x  = (const float*)d_in[0];
    const float* w1 = (const float*)d_in[1];
    const float* b1 = (const float*)d_in[2];
    const float* w2 = (const float*)d_in[3];
    const float* b2 = (const float*)d_in[4];
    const float* w3 = (const float*)d_in[5];
    const float* b3 = (const float*)d_in[6];
    const float* wd = (const float*)d_in[7];
    const float* bd = (const float*)d_in[8];
    float* out = (float*)d_out;

    // ws layout with aliasing (lifetimes; ~215.2 MB):
    //   s1pt u16 [40][129][130][64] @ 256         (85,862,400)  conv1 -> conv2
    //   p3   f32 [40*256*1024]      @ 256         (41,943,040)  conv3 -> lif_mean1 (overlays s1pt)
    //   p2   f32 [40][4096][128]    @ 85,862,656  (83,886,080)  conv2 -> lif_s2_t
    //   pooled f32                  @ 85,862,656  (4,194,304)   lif_mean1 -> det (overlays p2)
    //   s2pt u16 [40][65][65][128]  @ 169,748,736 (43,264,000)  lif_s2_t -> conv3
    //   wt2b u16 [2][27][4096]      @ 213,012,736 (442,368)
    //   wt3b u16 [4][27][8192]      @ 213,455,104 (1,769,472)   end 215,224,576
    uint8_t* wsb = (uint8_t*)d_ws;
    unsigned short* s1pt = (unsigned short*)(wsb + 256);
    float*   p3     = (float*)(wsb + 256);
    float*   p2     = (float*)(wsb + 85862656u);
    float*   pooled = (float*)(wsb + 85862656u);
    unsigned short* s2pt = (unsigned short*)(wsb + 169748736u);
    unsigned short* wt2b = (unsigned short*)(wsb + 213012736u);
    unsigned short* wt3b = (unsigned short*)(wsb + 213455104u);

    float alpha, beta;
    { uint32_t ab = 0x3F7383C6u; memcpy(&alpha, &ab, 4); }  // e^-0.05f
    { uint32_t bb = 0x3F519857u; memcpy(&beta,  &bb, 4); }  // e^-0.2f

    zpad1t<<<40, 256, 0, stream>>>((uint32_t*)s1pt);
    zpad3b<<<40, 256, 0, stream>>>((uint32_t*)s2pt);
    wtrans2c<<<288, 256, 0, stream>>>(w2, wt2b);
    wtrans3c<<<1152, 256, 0, stream>>>(w3, wt3b);
    conv1_lif<<<dim3(16, 128, 4), 256, 0, stream>>>(x, w1, b1, s1pt, alpha, beta);
    // L2 conv MFMA: grid (64 rows, 2 co-groups, 40 frames) = 5120 blocks
    conv2_mfma<<<dim3(64, 2, 40), 256, 0, stream>>>(s1pt, wt2b, p2);
    lif_s2_t<<<dim3(512, 1, 4), 256, 0, stream>>>(p2, b2, s2pt, alpha, beta);
    // L3 conv MFMA: grid (16 row-pairs, 4 co-groups, 40 frames) = 2560 blocks
    conv3_mfma3<<<dim3(16, 4, 40), 256, 0, stream>>>(s2pt, wt3b, p3);
    lif_mean1<<<dim3(1, 256, 4), 256, 0, stream>>>(p3, b3, pooled, alpha, beta);
    det_conv<<<dim3(16, 4, 4), 256, 0, stream>>>(pooled, wd, bd, out);
}

// Round 6
// 323.545 us; speedup vs baseline: 2.3896x; 1.8026x over previous
//
#include <hip/hip_runtime.h>
#include <stdint.h>
#include <string.h>
#include <cmath>

// SpikingYOLO round 24: attack the LOAD stream (R21/22/23 proved schedule
// doesn't matter -> load-request-throughput bound). (1) Spike planes
// re-laid parity-split + ci-chunked so every A-fragment is one dense
// contiguous 1KB wave-load. (2) 8-wave blocks (64px x 128co): A staged ONCE
// per block into ring-3 LDS (1 global_load_lds per wave), eliminating the
// 4x A duplication; B per-wave in regs. 7 vm ops/phase (was 14), VMCNT(7),
// one barrier/phase. Accumulation order per output IDENTICAL to R23 ->
// absmax expected unchanged (0.006835938).

#define BB 4
#define TT 10

typedef short bf16x8 __attribute__((ext_vector_type(8)));
typedef float f32x4  __attribute__((ext_vector_type(4)));

#define MFMA16(a, b, c) __builtin_amdgcn_mfma_f32_16x16x32_bf16((a), (b), (c), 0, 0, 0)

// s1p2: [40][129 rows][parity 2][cih 2][col2 66][cil 32] bf16
//   row stride 8448 elems, parity 4224, cih 2112; plane 1,089,792 elems.
//   row index = input row + 1; parity1 holds odd cols (col2=(col+1)/2),
//   parity0 even cols (col2=col/2). col -1 -> parity1 col2 0 (zeroed).
// s2p3: [40][65][parity 2][cih 4][col2 34][cil 32] bf16
//   row stride 8704 elems, parity 4352, cih 1088; plane 565,760 elems.

// ---------------- zero pads of s1p2 (u32 view): plane 544,896 u32, row 4224.
// row 0 fully + parity1 col2 0 (cih 0,1) of rows 1..128.
__global__ __launch_bounds__(256) void zpad1v(uint32_t* __restrict__ buf) {
    uint32_t* p = buf + (size_t)blockIdx.x * 544896u;
    for (int i = threadIdx.x; i < 8320; i += 256) {
        if (i < 4224) p[i] = 0u;
        else {
            int j = i - 4224;
            int row = 1 + (j >> 5), cih = (j >> 4) & 1, e = j & 15;
            p[row * 4224 + 2112 + cih * 1056 + e] = 0u;
        }
    }
}

// ---------------- zero pads of s2p3 (u32 view): plane 282,880 u32, row 4352.
// row 0 fully + parity1 col2 0 (cih 0..3) of rows 1..64.
__global__ __launch_bounds__(256) void zpad3v(uint32_t* __restrict__ buf) {
    uint32_t* p = buf + (size_t)blockIdx.x * 282880u;
    for (int i = threadIdx.x; i < 8448; i += 256) {
        if (i < 4352) p[i] = 0u;
        else {
            int j = i - 4352;
            int row = 1 + (j >> 6), cih = (j >> 4) & 3, e = j & 15;
            p[row * 4352 + 2176 + cih * 544 + e] = 0u;
        }
    }
}

// ---------------------------------------------------------------- conv1+LIF
// LIF arithmetic bit-identical to R9..R23; stores bf16 spike into s1p2.
__global__ __launch_bounds__(256) void conv1_lif(
    const float* __restrict__ x,    // [4,2,128,128,10]
    const float* __restrict__ w1,   // [64,2,3,3]
    const float* __restrict__ b1,   // [64]
    unsigned short* __restrict__ s1p2,
    float alpha, float beta)
{
    __shared__ float xs[2][3][10][10];   // [ci][kh][wi][t]
    __shared__ float wsh[18][64];        // [tap][co]
    const int tid = threadIdx.x;
    const int b = blockIdx.z, h = blockIdx.y, w0 = blockIdx.x * 8;

    for (int i = tid; i < 1152; i += 256) {
        int co = i & 63, tap = i >> 6;
        wsh[tap][co] = w1[co * 18 + tap];
    }
    for (int i = tid; i < 600; i += 256) {
        int t = i % 10; int rest = i / 10;
        int wi = rest % 10; rest /= 10;
        int kh = rest % 3; int ci = rest / 3;
        int hh = h - 1 + kh, ww = w0 - 1 + wi;
        float v = 0.f;
        if (hh >= 0 && hh < 128 && ww >= 0 && ww < 128)
            v = x[(((b * 2 + ci) * 128 + hh) * 128 + ww) * 10 + t];
        xs[ci][kh][wi][t] = v;
    }
    __syncthreads();

    const int px  = tid & 7;
    const int cog = (tid >> 3) * 2;
    float acc[2][10];
#pragma unroll
    for (int c = 0; c < 2; ++c)
#pragma unroll
        for (int t = 0; t < 10; ++t) acc[c][t] = 0.f;

#pragma unroll
    for (int tap = 0; tap < 18; ++tap) {
        const int ci = tap / 9, kh = (tap % 9) / 3, kw = tap % 3;
        float2 wv = *(const float2*)&wsh[tap][cog];
#pragma unroll
        for (int t = 0; t < 10; ++t) {
            float xv = xs[ci][kh][px + kw][t];
            acc[0][t] = __fmaf_rn(wv.x, xv, acc[0][t]);
            acc[1][t] = __fmaf_rn(wv.y, xv, acc[1][t]);
        }
    }
    const int col = w0 + px;
    const int pr  = col & 1;
    const int col2 = (col + pr) >> 1;
#pragma unroll
    for (int c = 0; c < 2; ++c) {
        const int co = cog + c;
        const float bv = b1[co];
        unsigned short* dst = s1p2 + (uint32_t)0
            + (h + 1) * 8448u + pr * 4224u + (co >> 5) * 2112u
            + col2 * 32u + (co & 31);
        float syn = 0.f, mem = 0.f;
#pragma unroll
        for (int t = 0; t < 10; ++t) {
            float cur = __fadd_rn(acc[c][t], bv);
            syn = __fadd_rn(__fmul_rn(beta, syn), cur);
            mem = __fadd_rn(__fmul_rn(alpha, mem), syn);
            bool sc = (mem >= 1.0f);
            float sp = sc ? 1.0f : 0.0f;
            mem = __fsub_rn(mem, sp);
            dst[(uint32_t)(t * BB + b) * 1089792u] =
                sc ? (unsigned short)0x3F80 : (unsigned short)0;
        }
    }
}

// --------- w2 -> 3-term bf16 split, layout [cobi(2)][tap(9)][term(3)]
// [4096-elem tile] (unchanged from R20..R23).
__global__ __launch_bounds__(256) void wtrans2c(
    const float* __restrict__ w2, unsigned short* __restrict__ wtb)
{
    int i = blockIdx.x * 256 + threadIdx.x;
    if (i >= 73728) return;                  // 128*64*9
    int co  = i / 576;
    int rem = i - co * 576;
    int ci  = rem / 9;
    int tap = rem - ci * 9;
    float w = w2[i];                         // [co][ci][kh][kw]
    uint32_t uw  = __float_as_uint(w);
    uint32_t h16 = (uw + 0x7FFFu + ((uw >> 16) & 1u)) >> 16;   // RNE bf16
    float hf = __uint_as_float(h16 << 16);
    float r1 = w - hf;
    uint32_t ur1 = __float_as_uint(r1);
    uint32_t m16 = (ur1 + 0x7FFFu + ((ur1 >> 16) & 1u)) >> 16;
    float mf = __uint_as_float(m16 << 16);
    float r2 = r1 - mf;
    uint32_t ur2 = __float_as_uint(r2);
    uint32_t l16 = (ur2 + 0x7FFFu + ((ur2 >> 16) & 1u)) >> 16;

    int cobi = co >> 6, coL = co & 63;
    int wid = coL >> 4, l15 = coL & 15;
    int c = ci >> 5, r5 = ci & 31;
    int g = r5 >> 3, e = r5 & 7;
    size_t base = (size_t)(cobi * 27 + tap * 3) * 4096
                + (size_t)(((wid * 2 + c) * 64 + (g * 16 + l15)) * 8 + e);
    wtb[base]        = (unsigned short)h16;
    wtb[base + 4096] = (unsigned short)m16;
    wtb[base + 8192] = (unsigned short)l16;
}

// --------- w3 -> 3-term bf16 split, layout [cobi(4)][tap(9)][term(3)]
// [8192-elem tile] (unchanged from R20..R23).
__global__ __launch_bounds__(256) void wtrans3c(
    const float* __restrict__ w3, unsigned short* __restrict__ wtb)
{
    int i = blockIdx.x * 256 + threadIdx.x;
    if (i >= 294912) return;                 // 256*128*9
    int co  = i / 1152;
    int rem = i - co * 1152;
    int ci  = rem / 9;
    int tap = rem - ci * 9;
    float w = w3[i];                         // [co][ci][kh][kw]
    uint32_t uw  = __float_as_uint(w);
    uint32_t h16 = (uw + 0x7FFFu + ((uw >> 16) & 1u)) >> 16;
    float hf = __uint_as_float(h16 << 16);
    float r1 = w - hf;
    uint32_t ur1 = __float_as_uint(r1);
    uint32_t m16 = (ur1 + 0x7FFFu + ((ur1 >> 16) & 1u)) >> 16;
    float mf = __uint_as_float(m16 << 16);
    float r2 = r1 - mf;
    uint32_t ur2 = __float_as_uint(r2);
    uint32_t l16 = (ur2 + 0x7FFFu + ((ur2 >> 16) & 1u)) >> 16;

    int cobi = co >> 6, coL = co & 63;
    int wq = coL >> 4, l15 = coL & 15;
    int cc = ci >> 5, r5 = ci & 31;
    int g = r5 >> 3, e = r5 & 7;
    size_t base = (size_t)(cobi * 27 + tap * 3) * 8192
                + (size_t)(((wq * 4 + cc) * 64 + (g * 16 + l15)) * 8 + e);
    wtb[base]         = (unsigned short)h16;
    wtb[base + 8192]  = (unsigned short)m16;
    wtb[base + 16384] = (unsigned short)l16;
}

#define VMCNT(n) do { __builtin_amdgcn_sched_barrier(0); \
    asm volatile("s_waitcnt vmcnt(" #n ")" ::: "memory"); \
    __builtin_amdgcn_sched_barrier(0); } while (0)
#define SB() __builtin_amdgcn_sched_barrier(0)
#define BARR() do { __builtin_amdgcn_sched_barrier(0); \
    __builtin_amdgcn_s_barrier(); \
    __builtin_amdgcn_sched_barrier(0); } while (0)
#define PRIO1() __builtin_amdgcn_s_setprio(1)
#define PRIO0() __builtin_amdgcn_s_setprio(0)

// ------------------- L2 conv via MFMA. 8-wave block, 64 px (1 row) x 128 co.
// Per phase(=tap): wave stages its 1 A-frag (1KB dense) into ring-3 LDS slot,
// loads its 6 B-frags to regs (dbuf); VMCNT(7); barrier; 8 ds_read_b128 +
// 24 MFMA. A-duplication eliminated. Per-output accum order == R23.
__global__ __launch_bounds__(512) void conv2_mfma(
    const unsigned short* __restrict__ s1p2,
    const unsigned short* __restrict__ wtb,   // [2][27][4096]
    float* __restrict__ p2)                   // [40][4096][128]
{
    __shared__ alignas(16) unsigned short Bs[3][4096];   // ring-3 x 8KB
    const int tid  = threadIdx.x;
    const int lane = tid & 63, w = tid >> 6;
    const int r = lane & 15, g = lane >> 4;
    const int f = blockIdx.z;
    const int hb = blockIdx.x;                 // output row 0..63

    const unsigned short* fb = s1p2 + (uint32_t)f * 1089792u;
    const unsigned short* wB = wtb + (uint32_t)(w >> 2) * (27u * 4096u)
                             + (uint32_t)(w & 3) * 1024u + (uint32_t)lane * 8u;
    const uint32_t lfo = (uint32_t)(r * 32 + g * 8);   // in-frag lane offset

    f32x4 acc[4];
#pragma unroll
    for (int mt = 0; mt < 4; ++mt) acc[mt] = (f32x4){0.f, 0.f, 0.f, 0.f};
    bf16x8 bA[6], bB[6];

#define STAGE2(tap_, slot_) do { \
    const int kh_ = (tap_) / 3, kw_ = (tap_) % 3; \
    const int p_ = (kw_ == 1) ? 0 : 1; \
    const int cf_ = (kw_ == 2) ? 1 : 0; \
    const int mt_ = w >> 1, c_ = w & 1; \
    const unsigned short* src_ = fb + (uint32_t)(2 * hb + kh_) * 8448u \
        + (uint32_t)p_ * 4224u + (uint32_t)c_ * 2112u \
        + (uint32_t)(mt_ * 16 + cf_) * 32u + lfo; \
    __builtin_amdgcn_global_load_lds( \
        (const __attribute__((address_space(1))) unsigned int*)(const void*)src_, \
        (__attribute__((address_space(3))) unsigned int*)(void*)(&Bs[slot_][w * 512]), \
        16, 0, 0); \
} while (0)

#define LOADB2(tap_, DST) do { _Pragma("unroll") \
    for (int t_ = 0; t_ < 3; ++t_) { _Pragma("unroll") \
        for (int c_ = 0; c_ < 2; ++c_) \
            DST[t_ * 2 + c_] = *(const bf16x8*)(wB + (uint32_t)((tap_) * 3 + t_) * 4096u + c_ * 512u); \
    } } while (0)

#define COMP2(slot_, BU) do { \
    bf16x8 af_[8]; \
    _Pragma("unroll") \
    for (int q_ = 0; q_ < 8; ++q_) \
        af_[q_] = *(const bf16x8*)&Bs[slot_][q_ * 512 + lane * 8]; \
    _Pragma("unroll") \
    for (int t_ = 0; t_ < 3; ++t_) { _Pragma("unroll") \
        for (int c_ = 0; c_ < 2; ++c_) { \
            bf16x8 b_ = BU[t_ * 2 + c_]; \
            acc[0] = MFMA16(b_, af_[0 + c_], acc[0]); \
            acc[1] = MFMA16(b_, af_[2 + c_], acc[1]); \
            acc[2] = MFMA16(b_, af_[4 + c_], acc[2]); \
            acc[3] = MFMA16(b_, af_[6 + c_], acc[3]); \
        } } } while (0)

#define PH2(tap_, snxt_, scur_, BU, BN) do { \
    SB(); STAGE2((tap_) + 1, snxt_); LOADB2((tap_) + 1, BN); SB(); \
    VMCNT(7); BARR(); \
    PRIO1(); COMP2(scur_, BU); PRIO0(); SB(); \
} while (0)

    STAGE2(0, 0); LOADB2(0, bA);
    PH2(0, 1, 0, bA, bB); PH2(1, 2, 1, bB, bA); PH2(2, 0, 2, bA, bB);
    PH2(3, 1, 0, bB, bA); PH2(4, 2, 1, bA, bB); PH2(5, 0, 2, bB, bA);
    PH2(6, 1, 0, bA, bB); PH2(7, 2, 1, bB, bA);
    // tap 8 tail (slot 2, bA)
    SB(); VMCNT(0); BARR();
    PRIO1(); COMP2(2, bA); PRIO0();

#pragma unroll
    for (int mt = 0; mt < 4; ++mt)
        *(f32x4*)&p2[((uint32_t)f * 4096u + hb * 64 + mt * 16 + r) * 128u
                     + w * 16 + g * 4] = acc[mt];
#undef STAGE2
#undef LOADB2
#undef COMP2
#undef PH2
}

// ---------------------- LIF layer 2: MFMA partial -> bf16 spikes (s2p3).
__global__ __launch_bounds__(256) void lif_s2_t(
    const float* __restrict__ pa, const float* __restrict__ bias,
    unsigned short* __restrict__ s2p3, float alpha, float beta)
{
    const int tid = threadIdx.x;
    const int b   = blockIdx.z;
    const int px  = blockIdx.x * 8 + (tid >> 5);
    const int co0 = (tid & 31) * 4;
    const int h = px >> 6, w = px & 63;
    float4 bv = *(const float4*)&bias[co0];
    const float bva[4] = {bv.x, bv.y, bv.z, bv.w};
    float syn[4] = {0.f,0.f,0.f,0.f}, mem[4] = {0.f,0.f,0.f,0.f};
    const int pr = w & 1;
    const int col2 = (w + pr) >> 1;
    unsigned short* sp = s2p3 + (uint32_t)(h + 1) * 8704u + pr * 4352u
                       + (co0 >> 5) * 1088u + col2 * 32u + (co0 & 31);
    for (int t = 0; t < TT; ++t) {
        const int f = t * BB + b;
        const uint32_t idx = ((uint32_t)f * 4096u + px) * 128u + co0;
        float4 A = *(const float4*)&pa[idx];
        const float va[4] = {A.x, A.y, A.z, A.w};
        uint32_t pk[2] = {0u, 0u};
#pragma unroll
        for (int j = 0; j < 4; ++j) {
            float c = __fadd_rn(va[j], bva[j]);
            syn[j] = __fadd_rn(__fmul_rn(beta, syn[j]), c);
            mem[j] = __fadd_rn(__fmul_rn(alpha, mem[j]), syn[j]);
            bool sc = (mem[j] >= 1.0f);
            mem[j] = __fsub_rn(mem[j], sc ? 1.0f : 0.0f);
            pk[j >> 1] |= (sc ? 0x3F80u : 0u) << ((j & 1) * 16);
        }
        *(uint2*)(sp + (uint32_t)f * 565760u) = make_uint2(pk[0], pk[1]);
    }
}

// ------------------- L3 conv via MFMA. 8-wave block, 64 px (2 rows) x 128 co.
// 18 half-tap phases; per phase: 1 stage + 6 B loads, VMCNT(7), barrier,
// 8 ds_read, 24 MFMA. Accum order per output identical to R23.
__global__ __launch_bounds__(512) void conv3_mfma3(
    const unsigned short* __restrict__ s2p3,
    const unsigned short* __restrict__ wtb,   // [4][27][8192]
    float* __restrict__ p3)                   // [40][256][32][32]
{
    __shared__ alignas(16) unsigned short Bs[3][4096];   // ring-3 x 8KB
    const int tid  = threadIdx.x;
    const int lane = tid & 63, w = tid >> 6;
    const int r = lane & 15, g = lane >> 4;
    const int f = blockIdx.z, cb2 = blockIdx.y;
    const int h0 = blockIdx.x * 2;

    const unsigned short* fb = s2p3 + (uint32_t)f * 565760u;
    const unsigned short* wB = wtb + (uint32_t)(cb2 * 2 + (w >> 2)) * (27u * 8192u)
                             + (uint32_t)(w & 3) * 2048u + (uint32_t)lane * 8u;
    const uint32_t lfo = (uint32_t)(r * 32 + g * 8);

    f32x4 acc[4];
#pragma unroll
    for (int mt = 0; mt < 4; ++mt) acc[mt] = (f32x4){0.f, 0.f, 0.f, 0.f};
    bf16x8 bA[6], bB[6];

#define STAGE3(tap_, half_, slot_) do { \
    const int kh_ = (tap_) / 3, kw_ = (tap_) % 3; \
    const int p_ = (kw_ == 1) ? 0 : 1; \
    const int cf_ = (kw_ == 2) ? 1 : 0; \
    const int mt_ = w >> 1, j_ = w & 1; \
    const unsigned short* src_ = fb \
        + (uint32_t)(2 * (h0 + (mt_ >> 1)) + kh_) * 8704u \
        + (uint32_t)p_ * 4352u + (uint32_t)((half_) * 2 + j_) * 1088u \
        + (uint32_t)((mt_ & 1) * 16 + cf_) * 32u + lfo; \
    __builtin_amdgcn_global_load_lds( \
        (const __attribute__((address_space(1))) unsigned int*)(const void*)src_, \
        (__attribute__((address_space(3))) unsigned int*)(void*)(&Bs[slot_][w * 512]), \
        16, 0, 0); \
} while (0)

#define LOADB3(tap_, half_, DST) do { _Pragma("unroll") \
    for (int t_ = 0; t_ < 3; ++t_) { _Pragma("unroll") \
        for (int j_ = 0; j_ < 2; ++j_) \
            DST[t_ * 2 + j_] = *(const bf16x8*)(wB + (uint32_t)((tap_) * 3 + t_) * 8192u \
                + (uint32_t)((half_) * 2 + j_) * 512u); \
    } } while (0)

#define COMP3(slot_, BU) do { \
    bf16x8 af_[8]; \
    _Pragma("unroll") \
    for (int q_ = 0; q_ < 8; ++q_) \
        af_[q_] = *(const bf16x8*)&Bs[slot_][q_ * 512 + lane * 8]; \
    _Pragma("unroll") \
    for (int t_ = 0; t_ < 3; ++t_) { _Pragma("unroll") \
        for (int j_ = 0; j_ < 2; ++j_) { \
            bf16x8 b_ = BU[t_ * 2 + j_]; \
            acc[0] = MFMA16(af_[0 + j_], b_, acc[0]); \
            acc[1] = MFMA16(af_[2 + j_], b_, acc[1]); \
            acc[2] = MFMA16(af_[4 + j_], b_, acc[2]); \
            acc[3] = MFMA16(af_[6 + j_], b_, acc[3]); \
        } } } while (0)

#define PH3(ntap_, nhalf_, snxt_, scur_, BU, BN) do { \
    SB(); STAGE3(ntap_, nhalf_, snxt_); LOADB3(ntap_, nhalf_, BN); SB(); \
    VMCNT(7); BARR(); \
    PRIO1(); COMP3(scur_, BU); PRIO0(); SB(); \
} while (0)

    STAGE3(0, 0, 0); LOADB3(0, 0, bA);
    PH3(0, 1, 1, 0, bA, bB); PH3(1, 0, 2, 1, bB, bA); PH3(1, 1, 0, 2, bA, bB);
    PH3(2, 0, 1, 0, bB, bA); PH3(2, 1, 2, 1, bA, bB); PH3(3, 0, 0, 2, bB, bA);
    PH3(3, 1, 1, 0, bA, bB); PH3(4, 0, 2, 1, bB, bA); PH3(4, 1, 0, 2, bA, bB);
    PH3(5, 0, 1, 0, bB, bA); PH3(5, 1, 2, 1, bA, bB); PH3(6, 0, 0, 2, bB, bA);
    PH3(6, 1, 1, 0, bA, bB); PH3(7, 0, 2, 1, bB, bA); PH3(7, 1, 0, 2, bA, bB);
    PH3(8, 0, 1, 0, bB, bA); PH3(8, 1, 2, 1, bA, bB);
    // phase 17 tail (tap 8, half 1): slot 2, bB
    SB(); VMCNT(0); BARR();
    PRIO1(); COMP3(2, bB); PRIO0();

#pragma unroll
    for (int mt = 0; mt < 4; ++mt) {
        const int hh = h0 + (mt >> 1);
        const int wc = (mt & 1) * 16 + g * 4;
        *(f32x4*)&p3[((uint32_t)(f * 256 + cb2 * 128 + w * 16 + r) * 32u + hh) * 32u + wc] = acc[mt];
    }
#undef STAGE3
#undef LOADB3
#undef COMP3
#undef PH3
}

// ---------------------- LIF + time-mean from the single conv3 buffer
__global__ __launch_bounds__(256) void lif_mean1(
    const float* __restrict__ p3, const float* __restrict__ bias,
    float* __restrict__ pooled, float alpha, float beta)
{
    const int px = (blockIdx.x * 256 + threadIdx.x) * 4;
    const int co = blockIdx.y;
    const int b  = blockIdx.z;
    const float bv = bias[co];
    float syn[4] = {0.f,0.f,0.f,0.f}, mem[4] = {0.f,0.f,0.f,0.f};
    float sum[4] = {0.f,0.f,0.f,0.f};
    for (int t = 0; t < TT; ++t) {
        const int idx = ((t * BB + b) * 256 + co) * 1024 + px;
        float4 a = *(const float4*)&p3[idx];
        const float va[4] = {a.x, a.y, a.z, a.w};
#pragma unroll
        for (int j = 0; j < 4; ++j) {
            float cu = __fadd_rn(va[j], bv);
            syn[j] = __fadd_rn(__fmul_rn(beta, syn[j]), cu);
            mem[j] = __fadd_rn(__fmul_rn(alpha, mem[j]), syn[j]);
            bool sc = (mem[j] >= 1.0f);
            float sp = sc ? 1.0f : 0.0f;
            mem[j] = __fsub_rn(mem[j], sp);
            sum[j] = __fadd_rn(sum[j], sp);
        }
    }
    *(float4*)&pooled[(b * 256 + co) * 1024 + px] =
        make_float4(sum[0] / 10.0f, sum[1] / 10.0f, sum[2] / 10.0f, sum[3] / 10.0f);
}

// ------------------------------------------------------------------ det 1x1
__global__ __launch_bounds__(256) void det_conv(
    const float* __restrict__ pooled, // [4,256,1024]
    const float* __restrict__ wd,     // [255,256]
    const float* __restrict__ bd,     // [255]
    float* __restrict__ out)          // [4,255,1024]
{
    __shared__ float wtl[16][64];
    __shared__ float ps[16][64];
    const int tid = threadIdx.x;
    const int b = blockIdx.z;
    const int o_base = blockIdx.y * 64;
    const int px_base = blockIdx.x * 64;
    const int o_off = (tid >> 4) * 4;
    const int px_off = (tid & 15) * 4;
    float acc[4][4];
#pragma unroll
    for (int c = 0; c < 4; ++c) {
        int o = o_base + o_off + c;
        float bv = (o < 255) ? bd[o] : 0.f;
#pragma unroll
        for (int j = 0; j < 4; ++j) acc[c][j] = bv;
    }
    for (int cc = 0; cc < 16; ++cc) {
        for (int k = tid; k < 1024; k += 256) {
            int o = k & 63, ci = k >> 6;
            wtl[ci][o] = (o_base + o < 255) ? wd[(o_base + o) * 256 + cc * 16 + ci] : 0.f;
            ps[ci][o] = pooled[(b * 256 + cc * 16 + ci) * 1024 + px_base + o];
        }
        __syncthreads();
#pragma unroll
        for (int ci = 0; ci < 16; ++ci) {
            float4 wv = *(const float4*)&wtl[ci][o_off];
            float4 sv = *(const float4*)&ps[ci][px_off];
            acc[0][0] += wv.x * sv.x; acc[0][1] += wv.x * sv.y;
            acc[0][2] += wv.x * sv.z; acc[0][3] += wv.x * sv.w;
            acc[1][0] += wv.y * sv.x; acc[1][1] += wv.y * sv.y;
            acc[1][2] += wv.y * sv.z; acc[1][3] += wv.y * sv.w;
            acc[2][0] += wv.z * sv.x; acc[2][1] += wv.z * sv.y;
            acc[2][2] += wv.z * sv.z; acc[2][3] += wv.z * sv.w;
            acc[3][0] += wv.w * sv.x; acc[3][1] += wv.w * sv.y;
            acc[3][2] += wv.w * sv.z; acc[3][3] += wv.w * sv.w;
        }
        __syncthreads();
    }
#pragma unroll
    for (int c = 0; c < 4; ++c) {
        int o = o_base + o_off + c;
        if (o < 255)
            *(float4*)&out[(b * 255 + o) * 1024 + px_base + px_off] =
                make_float4(acc[c][0], acc[c][1], acc[c][2], acc[c][3]);
    }
}

extern "C" void kernel_launch(void* const* d_in, const int* in_sizes, int n_in,
                              void* d_out, int out_size, void* d_ws, size_t ws_size,
                              hipStream_t stream) {
    const float* x  = (const float*)d_in[0];
    const float* w1 = (const float*)d_in[1];
    const float* b1 = (const float*)d_in[2];
    const float* w2 = (const float*)d_in[3];
    const float* b2 = (const float*)d_in[4];
    const float* w3 = (const float*)d_in[5];
    const float* b3 = (const float*)d_in[6];
    const float* wd = (const float*)d_in[7];
    const float* bd = (const float*)d_in[8];
    float* out = (float*)d_out;

    // ws layout with aliasing (lifetimes; ~218.5 MB):
    //   s1p2 u16 [40][1,089,792]   @ 256          (87,183,360)  conv1 -> conv2
    //   p3   f32 [40*256*1024]     @ 256          (41,943,040)  conv3 -> lif_mean1 (overlays s1p2)
    //   p2   f32 [40][4096][128]   @ 87,183,616   (83,886,080)  conv2 -> lif_s2_t
    //   pooled f32                 @ 87,183,616   (4,194,304)   lif_mean1 -> det (overlays p2)
    //   s2p3 u16 [40][565,760]     @ 171,069,696  (45,260,800)  lif_s2_t -> conv3
    //   wt2b u16 [2][27][4096]     @ 216,330,496  (442,368)
    //   wt3b u16 [4][27][8192]     @ 216,772,864  (1,769,472)   end 218,542,336
    uint8_t* wsb = (uint8_t*)d_ws;
    unsigned short* s1p2 = (unsigned short*)(wsb + 256);
    float*   p3     = (float*)(wsb + 256);
    float*   p2     = (float*)(wsb + 87183616u);
    float*   pooled = (float*)(wsb + 87183616u);
    unsigned short* s2p3 = (unsigned short*)(wsb + 171069696u);
    unsigned short* wt2b = (unsigned short*)(wsb + 216330496u);
    unsigned short* wt3b = (unsigned short*)(wsb + 216772864u);

    float alpha, beta;
    { uint32_t ab = 0x3F7383C6u; memcpy(&alpha, &ab, 4); }  // e^-0.05f
    { uint32_t bb = 0x3F519857u; memcpy(&beta,  &bb, 4); }  // e^-0.2f

    zpad1v<<<40, 256, 0, stream>>>((uint32_t*)s1p2);
    zpad3v<<<40, 256, 0, stream>>>((uint32_t*)s2p3);
    wtrans2c<<<288, 256, 0, stream>>>(w2, wt2b);
    wtrans3c<<<1152, 256, 0, stream>>>(w3, wt3b);
    conv1_lif<<<dim3(16, 128, 4), 256, 0, stream>>>(x, w1, b1, s1p2, alpha, beta);
    // L2 conv MFMA: grid (64 rows, 1, 40 frames), 512-thread blocks
    conv2_mfma<<<dim3(64, 1, 40), 512, 0, stream>>>(s1p2, wt2b, p2);
    lif_s2_t<<<dim3(512, 1, 4), 256, 0, stream>>>(p2, b2, s2p3, alpha, beta);
    // L3 conv MFMA: grid (16 row-pairs, 2 co-halves, 40 frames), 512 threads
    conv3_mfma3<<<dim3(16, 2, 40), 512, 0, stream>>>(s2p3, wt3b, p3);
    lif_mean1<<<dim3(1, 256, 4), 256, 0, stream>>>(p3, b3, pooled, alpha, beta);
    det_conv<<<dim3(16, 4, 4), 256, 0, stream>>>(pooled, wd, bd, out);
}